// Round 13
// baseline (614.334 us; speedup 1.0000x reference)
//
#include <hip/hip_runtime.h>
#include <hip/hip_bf16.h>
#include <math.h>

#define F 128

typedef __attribute__((ext_vector_type(8))) short bf16x8;
typedef __attribute__((ext_vector_type(4))) float f32x4;

// ------- row-normalize: xn = x/max(||x||,eps) (fp32 + bf16 copies) ----------
__global__ void k_normalize(const float* __restrict__ x, float* __restrict__ xn,
                            __hip_bfloat16* __restrict__ xnb, int N) {
  int wid = (blockIdx.x * blockDim.x + threadIdx.x) >> 6;  // one wave per node
  int lane = threadIdx.x & 63;
  if (wid >= N) return;
  const float2* src = (const float2*)(x + (size_t)wid * F);
  float2 v = src[lane];
  float ss = v.x * v.x + v.y * v.y;
#pragma unroll
  for (int m = 32; m >= 1; m >>= 1) ss += __shfl_xor(ss, m);
  float inv = 1.0f / fmaxf(sqrtf(ss), 1e-12f);
  float2 o; o.x = v.x * inv; o.y = v.y * inv;
  ((float2*)(xn + (size_t)wid * F))[lane] = o;
  __hip_bfloat162 ob;
  ob.x = __float2bfloat16(o.x); ob.y = __float2bfloat16(o.y);
  ((__hip_bfloat162*)(xnb + (size_t)wid * F))[lane] = ob;
}

// ============ CSR build: atomic-free two-level LDS counting sort ============
__global__ __launch_bounds__(256) void k_lhist(
    const int* __restrict__ keys, const int* __restrict__ perm,
    int* __restrict__ ghist, int* __restrict__ keyout, int nchunk, int E) {
  __shared__ int lh[256];
  int t = threadIdx.x, chunk = blockIdx.x;
  lh[t] = 0;
  __syncthreads();
  int base = chunk * 2048;
#pragma unroll
  for (int k = 0; k < 8; ++k) {
    int i = base + k * 256 + t;
    if (i < E) {
      int key = perm ? keys[perm[i]] : keys[i];
      if (keyout) keyout[i] = key;
      atomicAdd(&lh[key >> 8], 1);
    }
  }
  __syncthreads();
  ghist[t * nchunk + chunk] = lh[t];
}

__global__ void k_scan1(const int* __restrict__ cnt, int* __restrict__ partial,
                        int* __restrict__ bsum, int M) {
  __shared__ int sm[256];
  int t = threadIdx.x;
  int i = blockIdx.x * 256 + t;
  int val = (i < M) ? cnt[i] : 0;
  sm[t] = val;
  __syncthreads();
  for (int off = 1; off < 256; off <<= 1) {
    int v = (t >= off) ? sm[t - off] : 0;
    __syncthreads();
    sm[t] += v;
    __syncthreads();
  }
  if (i < M) partial[i] = sm[t] - val;  // exclusive
  if (t == 255) bsum[blockIdx.x] = sm[255];
}

__global__ void k_scan2(const int* __restrict__ bsum, int* __restrict__ boffs, int nb) {
  __shared__ int sm[256];
  int t = threadIdx.x;
  int carry = 0;
  for (int base = 0; base < nb; base += 256) {
    int idx = base + t;
    int val = (idx < nb) ? bsum[idx] : 0;
    sm[t] = val;
    __syncthreads();
    for (int off = 1; off < 256; off <<= 1) {
      int v = (t >= off) ? sm[t - off] : 0;
      __syncthreads();
      sm[t] += v;
      __syncthreads();
    }
    if (idx < nb) boffs[idx] = sm[t] - val + carry;
    carry += sm[255];
    __syncthreads();
  }
}

__global__ __launch_bounds__(256) void k_bucketize(
    const int* __restrict__ keys, const int* __restrict__ perm,
    const int* __restrict__ partial, const int* __restrict__ boffs,
    int* __restrict__ ebuck, int nchunk, int E) {
  __shared__ int lcur[256];
  int t = threadIdx.x, chunk = blockIdx.x;
  int idx = t * nchunk + chunk;
  lcur[t] = partial[idx] + boffs[idx >> 8];
  __syncthreads();
  int base = chunk * 2048;
#pragma unroll
  for (int k = 0; k < 8; ++k) {
    int i = base + k * 256 + t;
    if (i < E) {
      int key = perm ? keys[perm[i]] : keys[i];
      int pos = atomicAdd(&lcur[key >> 8], 1);
      ebuck[pos] = (i << 8) | (key & 255);
    }
  }
}

__global__ __launch_bounds__(256) void k_final_row(
    const int* __restrict__ ebuck, const int* __restrict__ partial,
    const int* __restrict__ boffs, int* __restrict__ perm_r,
    int* __restrict__ offs_r, int nchunk, int N, int E) {
  __shared__ int lh[256], sm[256], lscan[256];
  int t = threadIdx.x, b = blockIdx.x;
  int i0 = b * nchunk;
  int start = partial[i0] + boffs[i0 >> 8];
  int i1 = i0 + nchunk;
  int end = (b < 255) ? partial[i1] + boffs[i1 >> 8] : E;
  lh[t] = 0;
  __syncthreads();
  for (int p = start + t; p < end; p += 256) atomicAdd(&lh[ebuck[p] & 255], 1);
  __syncthreads();
  int val = lh[t];
  sm[t] = val;
  __syncthreads();
  for (int off = 1; off < 256; off <<= 1) {
    int v = (t >= off) ? sm[t - off] : 0;
    __syncthreads();
    sm[t] += v;
    __syncthreads();
  }
  lscan[t] = sm[t] - val;
  int node = b * 256 + t;
  if (node < N) offs_r[node] = start + lscan[t];
  if (b == 0 && t == 0) offs_r[N] = E;
  lh[t] = 0;
  __syncthreads();
  for (int p = start + t; p < end; p += 256) {
    int v = ebuck[p];
    int low = v & 255;
    int rk = atomicAdd(&lh[low], 1);
    perm_r[start + lscan[low] + rk] = v >> 8;
  }
}

__global__ __launch_bounds__(256) void k_final_col(
    const int* __restrict__ ebuck, const int* __restrict__ perm_r,
    const int* __restrict__ row, const int* __restrict__ partial,
    const int* __restrict__ boffs, int2* __restrict__ pstat,
    int* __restrict__ offs_c, int nchunk, int N, int E) {
  __shared__ int lh[256], sm[256], lscan[256];
  int t = threadIdx.x, b = blockIdx.x;
  int i0 = b * nchunk;
  int start = partial[i0] + boffs[i0 >> 8];
  int i1 = i0 + nchunk;
  int end = (b < 255) ? partial[i1] + boffs[i1 >> 8] : E;
  lh[t] = 0;
  __syncthreads();
  for (int p = start + t; p < end; p += 256) atomicAdd(&lh[ebuck[p] & 255], 1);
  __syncthreads();
  int val = lh[t];
  sm[t] = val;
  __syncthreads();
  for (int off = 1; off < 256; off <<= 1) {
    int v = (t >= off) ? sm[t - off] : 0;
    __syncthreads();
    sm[t] += v;
    __syncthreads();
  }
  lscan[t] = sm[t] - val;
  int node = b * 256 + t;
  if (node < N) offs_c[node] = start + lscan[t];
  if (b == 0 && t == 0) offs_c[N] = E;
  lh[t] = 0;
  __syncthreads();
  for (int p = start + t; p < end; p += 256) {
    int v = ebuck[p];
    int low = v & 255;
    int rp = v >> 8;                      // rowCSR slot (~ascending -> L2 locality)
    int e = perm_r[rp];
    int rk = atomicAdd(&lh[low], 1);
    int2 rec; rec.x = row[e]; rec.y = rp;
    pstat[start + lscan[low] + rk] = rec;
  }
}

// ------- fused per-row sims + weights, MFMA edition. One wave per row. ------
__global__ __launch_bounds__(256) void k_simw(
    const float* __restrict__ xn, const __hip_bfloat16* __restrict__ xnb,
    const int* __restrict__ colof_r, const int* __restrict__ offs_r,
    float* __restrict__ adjr, float* __restrict__ wgr,
    const float* __restrict__ gate, int layer, int N) {
  int w = threadIdx.x >> 6;   // wave 0..3, one row each
  int l = threadIdx.x & 63;
  int r = blockIdx.x * 4 + w;
  __shared__ float sims[4][320];
  __shared__ int scol[4][320];
  if (r >= N) return;
  int p0 = offs_r[r], p1 = offs_r[r + 1];
  int ne = p1 - p0;                     // ~17 (Poisson(16) + self loop), <320
  int quad = l >> 4;
  int m = l & 15;
  int qoff = quad * 8;
  const __hip_bfloat16* xr = xnb + (size_t)r * F;
  bf16x8 b0 = *(const bf16x8*)(xr + 0 * 32 + qoff);   // 16-lane broadcast loads
  bf16x8 b1 = *(const bf16x8*)(xr + 1 * 32 + qoff);
  bf16x8 b2 = *(const bf16x8*)(xr + 2 * 32 + qoff);
  bf16x8 b3 = *(const bf16x8*)(xr + 3 * 32 + qoff);
  for (int tb = 0; tb < ne; tb += 16) {
    int ii = tb + m; if (ii > ne - 1) ii = ne - 1;     // clamp (extra rows ignored)
    int cm = colof_r[p0 + ii];
    if (quad == 0 && tb + m < ne) scol[w][tb + m] = cm;
    const __hip_bfloat16* xc = xnb + (size_t)cm * F;
    bf16x8 a0 = *(const bf16x8*)(xc + 0 * 32 + qoff);  // 4 independent 16B gathers
    bf16x8 a1 = *(const bf16x8*)(xc + 1 * 32 + qoff);
    bf16x8 a2 = *(const bf16x8*)(xc + 2 * 32 + qoff);
    bf16x8 a3 = *(const bf16x8*)(xc + 3 * 32 + qoff);
    f32x4 acc = {0.f, 0.f, 0.f, 0.f};
    acc = __builtin_amdgcn_mfma_f32_16x16x32_bf16(a0, b0, acc, 0, 0, 0);
    acc = __builtin_amdgcn_mfma_f32_16x16x32_bf16(a1, b1, acc, 0, 0, 0);
    acc = __builtin_amdgcn_mfma_f32_16x16x32_bf16(a2, b2, acc, 0, 0, 0);
    acc = __builtin_amdgcn_mfma_f32_16x16x32_bf16(a3, b3, acc, 0, 0, 0);
    if (m == 0) {                       // lanes 0,16,32,48 hold rows quad*4+reg
#pragma unroll
      for (int reg = 0; reg < 4; ++reg) {
        int i = tb + quad * 4 + reg;
        if (i < ne) sims[w][i] = acc[reg];
      }
    }
  }
  // pass 2: guard-band fp32 recompute + threshold + rowsum/deg (one wave).
  float vsum = 0.f; int cn = 0;
  for (int base = 0; base < ne; base += 64) {
    int i = base + l;
    bool have = i < ne;
    float s = have ? sims[w][i] : 0.f;
    int c = have ? scol[w][i] : r;
    bool self = (c == r);
    bool flag = have && !self && fabsf(s - 0.1f) < 0.01f;
    unsigned long long mask = __ballot(flag);
    while (mask) {                      // ~0.8 flagged edge/row: wave-coop fp32 dot
      int src = __ffsll(mask) - 1;
      mask &= mask - 1;
      int cc = __shfl(c, src);
      float2 ar = ((const float2*)(xn + (size_t)r * F))[l];
      float2 bc = ((const float2*)(xn + (size_t)cc * F))[l];
      float d = ar.x * bc.x + ar.y * bc.y;
#pragma unroll
      for (int mm = 32; mm >= 1; mm >>= 1) d += __shfl_xor(d, mm);
      if (l == src) s = d;
    }
    if (self || s < 0.1f) s = 0.f;
    if (have) sims[w][i] = s;
    vsum += s;
    cn += (s > 0.f) ? 1 : 0;
  }
#pragma unroll
  for (int mm = 32; mm >= 1; mm >>= 1) {
    vsum += __shfl_xor(vsum, mm);
    cn += __shfl_xor(cn, mm);
  }
  float rs = vsum;
  float lam = 1.0f / (float)(cn + 1);
  float gg = (layer > 0) ? gate[layer - 1] : 0.f;
  for (int i = l; i < ne; i += 64) {
    int c = scol[w][i];
    float s = sims[w][i];
    float sn = (rs > 0.f) ? s / rs : 0.f;
    float wv = (c == r) ? lam : sn;
    wv = expf(wv);                      // thresholded edges get exp(0)=1
    float wc;
    if (layer == 0) { adjr[p0 + i] = wv; wc = wv; }
    else { wc = gg * adjr[p0 + i] + (1.f - gg) * wv; }
    wgr[p0 + i] = wc;                   // sequential write; NO atomics
  }
}

// ---- dinv[c] = rsqrt(sum of wc over col segment); no atomics ---------------
__global__ __launch_bounds__(256) void k_colw(
    const int2* __restrict__ pstat, const float* __restrict__ wgr,
    const int* __restrict__ offs_c, float* __restrict__ dinv, int N) {
  int c = blockIdx.x * 256 + threadIdx.x;
  if (c >= N) return;
  int p0 = offs_c[c], p1 = offs_c[c + 1];
  float s = 0.f;
  int p = p0;
  for (; p + 4 <= p1; p += 4) {        // 4 random L2 reads in flight
    int2 a = pstat[p], b = pstat[p + 1], d = pstat[p + 2], e = pstat[p + 3];
    s += wgr[a.y] + wgr[b.y] + wgr[d.y] + wgr[e.y];
  }
  for (; p < p1; ++p) s += wgr[pstat[p].y];
  dinv[c] = (s > 0.f) ? rsqrtf(s) : 0.f;
}

// ---- packed[p] = (row, dinv[r]*w*dinv[c]): per-edge norm computed ONCE -----
__global__ __launch_bounds__(256) void k_nrm(
    const int2* __restrict__ pstat, const float* __restrict__ wgr,
    const float* __restrict__ dinv, const int* __restrict__ offs_c,
    int2* __restrict__ packed, int N) {
  int c = blockIdx.x * 256 + threadIdx.x;
  if (c >= N) return;
  int p0 = offs_c[c], p1 = offs_c[c + 1];
  float dic = dinv[c];
  for (int p = p0; p < p1; ++p) {
    int2 s = pstat[p];
    float nrm = dinv[s.x] * wgr[s.y] * dic;   // 200KB + 3.4MB L2 tables
    int2 rec; rec.x = s.x; rec.y = __float_as_int(nrm);
    packed[p] = rec;                           // sequential 8B write
  }
}

// ---- GEMM: out_bf16[M,128] = A[M,128] @ W[128,128]; A fp32 or bf16 ---------
__global__ __launch_bounds__(256) void k_gemm128(const void* __restrict__ Av,
                                                 int a_bf16,
                                                 const float* __restrict__ W,
                                                 __hip_bfloat16* __restrict__ out, int M) {
  __shared__ float As[128][36];
  int t = threadIdx.x;
  int n0 = blockIdx.x * 32;
  for (int i = t; i < 32 * 128; i += 256) {
    int nn = i >> 7, kk = i & 127;
    int gn = n0 + nn;
    float v = 0.f;
    if (gn < M) {
      if (a_bf16) v = __bfloat162float(((const __hip_bfloat16*)Av)[(size_t)gn * 128 + kk]);
      else v = ((const float*)Av)[(size_t)gn * 128 + kk];
    }
    As[kk][nn] = v;
  }
  __syncthreads();
  int nb = (t >> 6) * 8;
  int j2 = (t & 63) * 2;
  float acc[8][2] = {};
  for (int k = 0; k < 128; ++k) {
    float4 a01 = *(const float4*)&As[k][nb];
    float4 a23 = *(const float4*)&As[k][nb + 4];
    float2 wv = *(const float2*)&W[k * 128 + j2];
    acc[0][0] += a01.x * wv.x; acc[0][1] += a01.x * wv.y;
    acc[1][0] += a01.y * wv.x; acc[1][1] += a01.y * wv.y;
    acc[2][0] += a01.z * wv.x; acc[2][1] += a01.z * wv.y;
    acc[3][0] += a01.w * wv.x; acc[3][1] += a01.w * wv.y;
    acc[4][0] += a23.x * wv.x; acc[4][1] += a23.x * wv.y;
    acc[5][0] += a23.y * wv.x; acc[5][1] += a23.y * wv.y;
    acc[6][0] += a23.z * wv.x; acc[6][1] += a23.z * wv.y;
    acc[7][0] += a23.w * wv.x; acc[7][1] += a23.w * wv.y;
  }
  __hip_bfloat162* o2 = (__hip_bfloat162*)out;
#pragma unroll
  for (int i = 0; i < 8; ++i) {
    int gn = n0 + nb + i;
    if (gn < M) {
      __hip_bfloat162 o;
      o.x = __float2bfloat16(acc[i][0]); o.y = __float2bfloat16(acc[i][1]);
      o2[(size_t)gn * 64 + (j2 >> 1)] = o;
    }
  }
}

// ---- GEMM: out_bf16[M,40] = A_bf16[M,128] @ W[128,40] ----------------------
__global__ __launch_bounds__(320) void k_gemm40(const __hip_bfloat16* __restrict__ A,
                                                const float* __restrict__ W,
                                                __hip_bfloat16* __restrict__ out,
                                                int M, int C) {
  __shared__ float As[128][68];
  int t = threadIdx.x;
  int n0 = blockIdx.x * 64;
  for (int i = t; i < 64 * 128; i += 320) {
    int nn = i >> 7, kk = i & 127;
    int gn = n0 + nn;
    As[kk][nn] = (gn < M) ? __bfloat162float(A[(size_t)gn * 128 + kk]) : 0.f;
  }
  __syncthreads();
  int gq = t / 40;
  int jc = t - gq * 40;
  int nb = gq * 8;
  float acc[8] = {};
  for (int k = 0; k < 128; ++k) {
    float4 a01 = *(const float4*)&As[k][nb];
    float4 a23 = *(const float4*)&As[k][nb + 4];
    float wv = W[k * C + jc];
    acc[0] += a01.x * wv; acc[1] += a01.y * wv; acc[2] += a01.z * wv; acc[3] += a01.w * wv;
    acc[4] += a23.x * wv; acc[5] += a23.y * wv; acc[6] += a23.z * wv; acc[7] += a23.w * wv;
  }
#pragma unroll
  for (int i = 0; i < 8; ++i) {
    int gn = n0 + nb + i;
    if (gn < M) out[(size_t)gn * C + jc] = __float2bfloat16(acc[i]);
  }
}

// ---- aggregation + bias + relu + row-normalize; nrm precomputed ------------
__global__ __launch_bounds__(256) void k_agg_norm(
    const __hip_bfloat162* __restrict__ hWb, const int2* __restrict__ packed,
    const int* __restrict__ offs_c, const float* __restrict__ bias,
    __hip_bfloat16* __restrict__ outb, float* __restrict__ xn,
    __hip_bfloat16* __restrict__ xnb, int N) {
  int w = threadIdx.x >> 6;
  int t = threadIdx.x & 63;
  int c = blockIdx.x * 4 + w;
  if (c >= N) return;
  int p0 = offs_c[c], p1 = offs_c[c + 1];
  float acc0 = bias[2 * t], acc1 = bias[2 * t + 1];
  int p = p0;
  for (; p + 8 <= p1; p += 8) {   // 8 row-gathers in flight
    int2 s[8];
    __hip_bfloat162 h[8];
#pragma unroll
    for (int k = 0; k < 8; ++k) s[k] = packed[p + k];
#pragma unroll
    for (int k = 0; k < 8; ++k) h[k] = hWb[(size_t)s[k].x * 64 + t];
#pragma unroll
    for (int k = 0; k < 8; ++k) {
      float n = __int_as_float(s[k].y);
      acc0 += n * __bfloat162float(h[k].x);
      acc1 += n * __bfloat162float(h[k].y);
    }
  }
  for (; p + 4 <= p1; p += 4) {
    int2 s0 = packed[p], s1 = packed[p + 1], s2 = packed[p + 2], s3 = packed[p + 3];
    __hip_bfloat162 h0 = hWb[(size_t)s0.x * 64 + t];
    __hip_bfloat162 h1 = hWb[(size_t)s1.x * 64 + t];
    __hip_bfloat162 h2 = hWb[(size_t)s2.x * 64 + t];
    __hip_bfloat162 h3 = hWb[(size_t)s3.x * 64 + t];
    float n0 = __int_as_float(s0.y), n1 = __int_as_float(s1.y);
    float n2 = __int_as_float(s2.y), n3 = __int_as_float(s3.y);
    acc0 += n0 * __bfloat162float(h0.x) + n1 * __bfloat162float(h1.x)
          + n2 * __bfloat162float(h2.x) + n3 * __bfloat162float(h3.x);
    acc1 += n0 * __bfloat162float(h0.y) + n1 * __bfloat162float(h1.y)
          + n2 * __bfloat162float(h2.y) + n3 * __bfloat162float(h3.y);
  }
  for (; p < p1; ++p) {
    int2 s0 = packed[p];
    __hip_bfloat162 h0 = hWb[(size_t)s0.x * 64 + t];
    float n0 = __int_as_float(s0.y);
    acc0 += n0 * __bfloat162float(h0.x);
    acc1 += n0 * __bfloat162float(h0.y);
  }
  acc0 = fmaxf(acc0, 0.f); acc1 = fmaxf(acc1, 0.f);
  __hip_bfloat162 oh;                    // h stored bf16 (GEMM input next layer)
  oh.x = __float2bfloat16(acc0); oh.y = __float2bfloat16(acc1);
  ((__hip_bfloat162*)outb)[(size_t)c * 64 + t] = oh;
  float ss = acc0 * acc0 + acc1 * acc1;
#pragma unroll
  for (int m = 32; m >= 1; m >>= 1) ss += __shfl_xor(ss, m);
  float inv = 1.0f / fmaxf(sqrtf(ss), 1e-12f);
  float2 on; on.x = acc0 * inv; on.y = acc1 * inv;
  ((float2*)xn)[(size_t)c * 64 + t] = on;
  __hip_bfloat162 ob;
  ob.x = __float2bfloat16(on.x); ob.y = __float2bfloat16(on.y);
  ((__hip_bfloat162*)xnb)[(size_t)c * 64 + t] = ob;
}

// ------- final aggregation + bias + log_softmax; nrm precomputed ------------
__global__ __launch_bounds__(256) void k_agg40_lsm(
    const __hip_bfloat16* __restrict__ hW, const int2* __restrict__ packed,
    const int* __restrict__ offs_c, const float* __restrict__ bias,
    float* __restrict__ out, int C, int N) {
  int w = threadIdx.x >> 6;
  int j = threadIdx.x & 63;
  int c = blockIdx.x * 4 + w;
  if (c >= N) return;
  int p0 = offs_c[c], p1 = offs_c[c + 1];
  bool act = j < C;
  int jj = act ? j : 0;
  float acc = act ? bias[jj] : 0.f;
  int p = p0;
  for (; p + 4 <= p1; p += 4) {
    int2 s0 = packed[p], s1 = packed[p + 1], s2 = packed[p + 2], s3 = packed[p + 3];
    float h0 = __bfloat162float(hW[(size_t)s0.x * C + jj]);
    float h1 = __bfloat162float(hW[(size_t)s1.x * C + jj]);
    float h2 = __bfloat162float(hW[(size_t)s2.x * C + jj]);
    float h3 = __bfloat162float(hW[(size_t)s3.x * C + jj]);
    acc += __int_as_float(s0.y) * h0 + __int_as_float(s1.y) * h1
         + __int_as_float(s2.y) * h2 + __int_as_float(s3.y) * h3;
  }
  for (; p < p1; ++p) {
    int2 s0 = packed[p];
    acc += __int_as_float(s0.y) * __bfloat162float(hW[(size_t)s0.x * C + jj]);
  }
  if (!act) acc = 0.f;
  float v = act ? acc : -3.0e38f;
#pragma unroll
  for (int m = 32; m >= 1; m >>= 1) v = fmaxf(v, __shfl_xor(v, m));
  float ex = act ? expf(acc - v) : 0.f;
#pragma unroll
  for (int m = 32; m >= 1; m >>= 1) ex += __shfl_xor(ex, m);
  if (act) out[(size_t)c * C + j] = acc - v - logf(ex);
}

extern "C" void kernel_launch(void* const* d_in, const int* in_sizes, int n_in,
                              void* d_out, int out_size, void* d_ws, size_t ws_size,
                              hipStream_t stream) {
  const float* x    = (const float*)d_in[0];
  const float* gate = (const float*)d_in[1];
  const float* W0   = (const float*)d_in[2];
  const float* b0   = (const float*)d_in[3];
  const float* W1   = (const float*)d_in[4];
  const float* b1   = (const float*)d_in[5];
  const float* W2   = (const float*)d_in[6];
  const float* b2   = (const float*)d_in[7];
  const int* eidx   = (const int*)d_in[8];
  int N = in_sizes[0] / 128;
  int E = in_sizes[8] / 2;
  int C = in_sizes[7];  // 40
  const int* row = eidx;
  const int* col = eidx + E;

  char* ws = (char*)d_ws;
  size_t off = 0;
  auto alloc = [&](size_t bytes) {
    char* p = ws + off;
    off += (bytes + 255) & ~(size_t)255;
    return p;
  };
  float* xn     = (float*)alloc((size_t)N * 128 * 4);
  __hip_bfloat16* xnb  = (__hip_bfloat16*)alloc((size_t)N * 128 * 2);
  __hip_bfloat16* bufC = (__hip_bfloat16*)alloc((size_t)N * 128 * 2);  // h, bf16
  __hip_bfloat16* hWb  = (__hip_bfloat16*)alloc((size_t)N * 128 * 2);
  float* adjr   = (float*)alloc((size_t)E * 4);    // layer-0 weights, row-CSR order
  float* wgr    = (float*)alloc((size_t)E * 4);    // gated weight, row-CSR order
  int*   perm_r = (int*)alloc((size_t)E * 4);
  int2*  pstat  = (int2*)alloc((size_t)E * 8);     // (row, rowCSR-slot) per col slot
  int2*  packed = (int2*)alloc((size_t)E * 8);     // (row, nrm) per col slot
  int*   colof_r= (int*)alloc((size_t)E * 4);
  int*   ebuck  = (int*)alloc((size_t)E * 4);      // bucket-partitioned packed ids
  int*   offs_c = (int*)alloc((size_t)(N + 1) * 4);
  int*   offs_r = (int*)alloc((size_t)(N + 1) * 4);
  float* dinv   = (float*)alloc((size_t)N * 4);

  int NCHUNK = (E + 2047) / 2048;
  int M      = 256 * NCHUNK;
  int*   ghist  = (int*)alloc((size_t)M * 4);
  int*   partial= (int*)alloc((size_t)M * 4);
  int*   bsum   = (int*)alloc((size_t)NCHUNK * 4);
  int*   boffs  = (int*)alloc((size_t)NCHUNK * 4);

  int NBUK = (N + 255) / 256;
  int nb1  = (N + 255) / 256;
  int nw4  = (N + 3) / 4;

  // ---- CSR build: atomic-free two-level counting sort (row, then col) ----
  k_lhist<<<NCHUNK, 256, 0, stream>>>(row, nullptr, ghist, nullptr, NCHUNK, E);
  k_scan1<<<NCHUNK, 256, 0, stream>>>(ghist, partial, bsum, M);
  k_scan2<<<1, 256, 0, stream>>>(bsum, boffs, NCHUNK);
  k_bucketize<<<NCHUNK, 256, 0, stream>>>(row, nullptr, partial, boffs, ebuck, NCHUNK, E);
  k_final_row<<<NBUK, 256, 0, stream>>>(ebuck, partial, boffs, perm_r, offs_r,
                                        NCHUNK, N, E);
  k_lhist<<<NCHUNK, 256, 0, stream>>>(col, perm_r, ghist, colof_r, NCHUNK, E);
  k_scan1<<<NCHUNK, 256, 0, stream>>>(ghist, partial, bsum, M);
  k_scan2<<<1, 256, 0, stream>>>(bsum, boffs, NCHUNK);
  k_bucketize<<<NCHUNK, 256, 0, stream>>>(col, perm_r, partial, boffs, ebuck, NCHUNK, E);
  k_final_col<<<NBUK, 256, 0, stream>>>(ebuck, perm_r, row, partial, boffs, pstat,
                                        offs_c, NCHUNK, N, E);

  for (int layer = 0; layer < 3; ++layer) {
    if (layer == 0) k_normalize<<<(N + 3) / 4, 256, 0, stream>>>(x, xn, xnb, N);
    k_simw<<<nw4, 256, 0, stream>>>(xn, xnb, colof_r, offs_r, adjr, wgr,
                                    gate, layer, N);
    k_colw<<<nb1, 256, 0, stream>>>(pstat, wgr, offs_c, dinv, N);
    k_nrm<<<nb1, 256, 0, stream>>>(pstat, wgr, dinv, offs_c, packed, N);
    if (layer < 2) {
      const float* W = (layer == 0) ? W0 : W1;
      const float* b = (layer == 0) ? b0 : b1;
      if (layer == 0)
        k_gemm128<<<(N + 31) / 32, 256, 0, stream>>>((const void*)x, 0, W, hWb, N);
      else
        k_gemm128<<<(N + 31) / 32, 256, 0, stream>>>((const void*)bufC, 1, W, hWb, N);
      k_agg_norm<<<nw4, 256, 0, stream>>>((const __hip_bfloat162*)hWb, packed, offs_c,
                                          b, bufC, xn, xnb, N);
    } else {
      k_gemm40<<<(N + 63) / 64, 320, 0, stream>>>(bufC, W2, hWb, N, C);
      k_agg40_lsm<<<nw4, 256, 0, stream>>>(hWb, packed, offs_c, b2, (float*)d_out, C, N);
    }
  }
}

// Round 14
// 601.309 us; speedup vs baseline: 1.0217x; 1.0217x over previous
//
#include <hip/hip_runtime.h>
#include <hip/hip_bf16.h>
#include <math.h>

#define F 128

typedef __attribute__((ext_vector_type(8))) short bf16x8;
typedef __attribute__((ext_vector_type(4))) float f32x4;

// ------- row-normalize: xn = x/max(||x||,eps) (fp32 + bf16 copies) ----------
__global__ void k_normalize(const float* __restrict__ x, float* __restrict__ xn,
                            __hip_bfloat16* __restrict__ xnb, int N) {
  int wid = (blockIdx.x * blockDim.x + threadIdx.x) >> 6;  // one wave per node
  int lane = threadIdx.x & 63;
  if (wid >= N) return;
  const float2* src = (const float2*)(x + (size_t)wid * F);
  float2 v = src[lane];
  float ss = v.x * v.x + v.y * v.y;
#pragma unroll
  for (int m = 32; m >= 1; m >>= 1) ss += __shfl_xor(ss, m);
  float inv = 1.0f / fmaxf(sqrtf(ss), 1e-12f);
  float2 o; o.x = v.x * inv; o.y = v.y * inv;
  ((float2*)(xn + (size_t)wid * F))[lane] = o;
  __hip_bfloat162 ob;
  ob.x = __float2bfloat16(o.x); ob.y = __float2bfloat16(o.y);
  ((__hip_bfloat162*)(xnb + (size_t)wid * F))[lane] = ob;
}

// ============ CSR build: atomic-free two-level LDS counting sort ============
__global__ __launch_bounds__(256) void k_lhist(
    const int* __restrict__ keys, const int* __restrict__ perm,
    int* __restrict__ ghist, int* __restrict__ keyout, int nchunk, int E) {
  __shared__ int lh[256];
  int t = threadIdx.x, chunk = blockIdx.x;
  lh[t] = 0;
  __syncthreads();
  int base = chunk * 2048;
#pragma unroll
  for (int k = 0; k < 8; ++k) {
    int i = base + k * 256 + t;
    if (i < E) {
      int key = perm ? keys[perm[i]] : keys[i];
      if (keyout) keyout[i] = key;
      atomicAdd(&lh[key >> 8], 1);
    }
  }
  __syncthreads();
  ghist[t * nchunk + chunk] = lh[t];
}

__global__ void k_scan1(const int* __restrict__ cnt, int* __restrict__ partial,
                        int* __restrict__ bsum, int M) {
  __shared__ int sm[256];
  int t = threadIdx.x;
  int i = blockIdx.x * 256 + t;
  int val = (i < M) ? cnt[i] : 0;
  sm[t] = val;
  __syncthreads();
  for (int off = 1; off < 256; off <<= 1) {
    int v = (t >= off) ? sm[t - off] : 0;
    __syncthreads();
    sm[t] += v;
    __syncthreads();
  }
  if (i < M) partial[i] = sm[t] - val;  // exclusive
  if (t == 255) bsum[blockIdx.x] = sm[255];
}

__global__ void k_scan2(const int* __restrict__ bsum, int* __restrict__ boffs, int nb) {
  __shared__ int sm[256];
  int t = threadIdx.x;
  int carry = 0;
  for (int base = 0; base < nb; base += 256) {
    int idx = base + t;
    int val = (idx < nb) ? bsum[idx] : 0;
    sm[t] = val;
    __syncthreads();
    for (int off = 1; off < 256; off <<= 1) {
      int v = (t >= off) ? sm[t - off] : 0;
      __syncthreads();
      sm[t] += v;
      __syncthreads();
    }
    if (idx < nb) boffs[idx] = sm[t] - val + carry;
    carry += sm[255];
    __syncthreads();
  }
}

__global__ __launch_bounds__(256) void k_bucketize(
    const int* __restrict__ keys, const int* __restrict__ perm,
    const int* __restrict__ partial, const int* __restrict__ boffs,
    int* __restrict__ ebuck, int nchunk, int E) {
  __shared__ int lcur[256];
  int t = threadIdx.x, chunk = blockIdx.x;
  int idx = t * nchunk + chunk;
  lcur[t] = partial[idx] + boffs[idx >> 8];
  __syncthreads();
  int base = chunk * 2048;
#pragma unroll
  for (int k = 0; k < 8; ++k) {
    int i = base + k * 256 + t;
    if (i < E) {
      int key = perm ? keys[perm[i]] : keys[i];
      int pos = atomicAdd(&lcur[key >> 8], 1);
      ebuck[pos] = (i << 8) | (key & 255);
    }
  }
}

__global__ __launch_bounds__(256) void k_final_row(
    const int* __restrict__ ebuck, const int* __restrict__ partial,
    const int* __restrict__ boffs, int* __restrict__ perm_r,
    int* __restrict__ offs_r, int nchunk, int N, int E) {
  __shared__ int lh[256], sm[256], lscan[256];
  int t = threadIdx.x, b = blockIdx.x;
  int i0 = b * nchunk;
  int start = partial[i0] + boffs[i0 >> 8];
  int i1 = i0 + nchunk;
  int end = (b < 255) ? partial[i1] + boffs[i1 >> 8] : E;
  lh[t] = 0;
  __syncthreads();
  for (int p = start + t; p < end; p += 256) atomicAdd(&lh[ebuck[p] & 255], 1);
  __syncthreads();
  int val = lh[t];
  sm[t] = val;
  __syncthreads();
  for (int off = 1; off < 256; off <<= 1) {
    int v = (t >= off) ? sm[t - off] : 0;
    __syncthreads();
    sm[t] += v;
    __syncthreads();
  }
  lscan[t] = sm[t] - val;
  int node = b * 256 + t;
  if (node < N) offs_r[node] = start + lscan[t];
  if (b == 0 && t == 0) offs_r[N] = E;
  lh[t] = 0;
  __syncthreads();
  for (int p = start + t; p < end; p += 256) {
    int v = ebuck[p];
    int low = v & 255;
    int rk = atomicAdd(&lh[low], 1);
    perm_r[start + lscan[low] + rk] = v >> 8;
  }
}

// per-bucket finalize (col): emits pstat[pc]=(row,rowCSR-slot) and colof_c[pc]
__global__ __launch_bounds__(256) void k_final_col(
    const int* __restrict__ ebuck, const int* __restrict__ perm_r,
    const int* __restrict__ row, const int* __restrict__ partial,
    const int* __restrict__ boffs, int2* __restrict__ pstat,
    int* __restrict__ colof_c, int* __restrict__ offs_c, int nchunk, int N, int E) {
  __shared__ int lh[256], sm[256], lscan[256];
  int t = threadIdx.x, b = blockIdx.x;
  int i0 = b * nchunk;
  int start = partial[i0] + boffs[i0 >> 8];
  int i1 = i0 + nchunk;
  int end = (b < 255) ? partial[i1] + boffs[i1 >> 8] : E;
  lh[t] = 0;
  __syncthreads();
  for (int p = start + t; p < end; p += 256) atomicAdd(&lh[ebuck[p] & 255], 1);
  __syncthreads();
  int val = lh[t];
  sm[t] = val;
  __syncthreads();
  for (int off = 1; off < 256; off <<= 1) {
    int v = (t >= off) ? sm[t - off] : 0;
    __syncthreads();
    sm[t] += v;
    __syncthreads();
  }
  lscan[t] = sm[t] - val;
  int node = b * 256 + t;
  if (node < N) offs_c[node] = start + lscan[t];
  if (b == 0 && t == 0) offs_c[N] = E;
  lh[t] = 0;
  __syncthreads();
  for (int p = start + t; p < end; p += 256) {
    int v = ebuck[p];
    int low = v & 255;
    int rp = v >> 8;                      // rowCSR slot (~ascending -> L2 locality)
    int e = perm_r[rp];
    int rk = atomicAdd(&lh[low], 1);
    int pos = start + lscan[low] + rk;
    int2 rec; rec.x = row[e]; rec.y = rp;
    pstat[pos] = rec;
    colof_c[pos] = b * 256 + low;
  }
}

// ------- fused per-row sims + weights, MFMA + 2-stage gather pipeline. ------
__global__ __launch_bounds__(256) void k_simw(
    const float* __restrict__ xn, const __hip_bfloat16* __restrict__ xnb,
    const int* __restrict__ colof_r, const int* __restrict__ offs_r,
    float* __restrict__ adjr, float* __restrict__ wgr,
    const float* __restrict__ gate, int layer, int N) {
  int w = threadIdx.x >> 6;   // wave 0..3, one row each
  int l = threadIdx.x & 63;
  int r = blockIdx.x * 4 + w;
  __shared__ float sims[4][320];
  __shared__ int scol[4][320];
  if (r >= N) return;
  int p0 = offs_r[r], p1 = offs_r[r + 1];
  int ne = p1 - p0;                     // ~17 (Poisson(16) + self loop), <320
  int quad = l >> 4;
  int m = l & 15;
  int qoff = quad * 8;
  const __hip_bfloat16* xr = xnb + (size_t)r * F;
  bf16x8 b0 = *(const bf16x8*)(xr + 0 * 32 + qoff);   // 16-lane broadcast loads
  bf16x8 b1 = *(const bf16x8*)(xr + 1 * 32 + qoff);
  bf16x8 b2 = *(const bf16x8*)(xr + 2 * 32 + qoff);
  bf16x8 b3 = *(const bf16x8*)(xr + 3 * 32 + qoff);
  int ntile = (ne + 15) >> 4;
  // stage-0 prefetch
  int cm;
  bf16x8 a0, a1, a2, a3;
  {
    int ii = (m > ne - 1) ? (ne - 1) : m;
    cm = colof_r[p0 + ii];
    const __hip_bfloat16* xc = xnb + (size_t)cm * F;
    a0 = *(const bf16x8*)(xc + 0 * 32 + qoff);
    a1 = *(const bf16x8*)(xc + 1 * 32 + qoff);
    a2 = *(const bf16x8*)(xc + 2 * 32 + qoff);
    a3 = *(const bf16x8*)(xc + 3 * 32 + qoff);
  }
  for (int tbi = 0; tbi < ntile; ++tbi) {
    int tb = tbi << 4;
    if (quad == 0 && tb + m < ne) scol[w][tb + m] = cm;
    bool more = (tbi + 1 < ntile);
    int cmn = 0;
    bf16x8 n0, n1, n2, n3;
    if (more) {                          // prefetch next tile during MFMA
      int ii = tb + 16 + m; if (ii > ne - 1) ii = ne - 1;
      cmn = colof_r[p0 + ii];
      const __hip_bfloat16* xc = xnb + (size_t)cmn * F;
      n0 = *(const bf16x8*)(xc + 0 * 32 + qoff);
      n1 = *(const bf16x8*)(xc + 1 * 32 + qoff);
      n2 = *(const bf16x8*)(xc + 2 * 32 + qoff);
      n3 = *(const bf16x8*)(xc + 3 * 32 + qoff);
    }
    f32x4 acc = {0.f, 0.f, 0.f, 0.f};
    acc = __builtin_amdgcn_mfma_f32_16x16x32_bf16(a0, b0, acc, 0, 0, 0);
    acc = __builtin_amdgcn_mfma_f32_16x16x32_bf16(a1, b1, acc, 0, 0, 0);
    acc = __builtin_amdgcn_mfma_f32_16x16x32_bf16(a2, b2, acc, 0, 0, 0);
    acc = __builtin_amdgcn_mfma_f32_16x16x32_bf16(a3, b3, acc, 0, 0, 0);
    if (m == 0) {                       // lanes 0,16,32,48 hold rows quad*4+reg
#pragma unroll
      for (int reg = 0; reg < 4; ++reg) {
        int i = tb + quad * 4 + reg;
        if (i < ne) sims[w][i] = acc[reg];
      }
    }
    if (more) { cm = cmn; a0 = n0; a1 = n1; a2 = n2; a3 = n3; }
  }
  // pass 2: guard-band fp32 recompute + threshold + rowsum/deg (one wave).
  // Band: bf16 rounding 2^-8/operand -> dot err <= 2^-7 = 0.0078 worst case
  // (Cauchy-Schwarz, unit vectors); +-0.01 covers it deterministically.
  float vsum = 0.f; int cn = 0;
  for (int base = 0; base < ne; base += 64) {
    int i = base + l;
    bool have = i < ne;
    float s = have ? sims[w][i] : 0.f;
    int c = have ? scol[w][i] : r;
    bool self = (c == r);
    bool flag = have && !self && fabsf(s - 0.1f) < 0.01f;
    unsigned long long mask = __ballot(flag);
    while (mask) {                      // ~0.8 flagged edge/row: wave-coop fp32 dot
      int src = __ffsll(mask) - 1;
      mask &= mask - 1;
      int cc = __shfl(c, src);
      float2 ar = ((const float2*)(xn + (size_t)r * F))[l];
      float2 bc = ((const float2*)(xn + (size_t)cc * F))[l];
      float d = ar.x * bc.x + ar.y * bc.y;
#pragma unroll
      for (int mm = 32; mm >= 1; mm >>= 1) d += __shfl_xor(d, mm);
      if (l == src) s = d;
    }
    if (self || s < 0.1f) s = 0.f;
    if (have) sims[w][i] = s;
    vsum += s;
    cn += (s > 0.f) ? 1 : 0;
  }
#pragma unroll
  for (int mm = 32; mm >= 1; mm >>= 1) {
    vsum += __shfl_xor(vsum, mm);
    cn += __shfl_xor(cn, mm);
  }
  float rs = vsum;
  float lam = 1.0f / (float)(cn + 1);
  float gg = (layer > 0) ? gate[layer - 1] : 0.f;
  for (int i = l; i < ne; i += 64) {
    int c = scol[w][i];
    float s = sims[w][i];
    float sn = (rs > 0.f) ? s / rs : 0.f;
    float wv = (c == r) ? lam : sn;
    wv = expf(wv);                      // thresholded edges get exp(0)=1
    float wc;
    if (layer == 0) { adjr[p0 + i] = wv; wc = wv; }
    else { wc = gg * adjr[p0 + i] + (1.f - gg) * wv; }
    wgr[p0 + i] = wc;                   // sequential write; NO atomics
  }
}

// ---- dinv[c] = rsqrt(sum of wc over col segment); no atomics ---------------
__global__ __launch_bounds__(256) void k_colw(
    const int2* __restrict__ pstat, const float* __restrict__ wgr,
    const int* __restrict__ offs_c, float* __restrict__ dinv, int N) {
  int c = blockIdx.x * 256 + threadIdx.x;
  if (c >= N) return;
  int p0 = offs_c[c], p1 = offs_c[c + 1];
  float s = 0.f;
  int p = p0;
  for (; p + 4 <= p1; p += 4) {        // 4 random L2 reads in flight
    int2 a = pstat[p], b = pstat[p + 1], d = pstat[p + 2], e = pstat[p + 3];
    s += wgr[a.y] + wgr[b.y] + wgr[d.y] + wgr[e.y];
  }
  for (; p < p1; ++p) s += wgr[pstat[p].y];
  dinv[c] = (s > 0.f) ? rsqrtf(s) : 0.f;
}

// ---- packed[p] = (row, dinv[r]*w*dinv[c]); EDGE-parallel, all loads indep --
__global__ __launch_bounds__(256) void k_nrm(
    const int2* __restrict__ pstat, const float* __restrict__ wgr,
    const float* __restrict__ dinv, const int* __restrict__ colof_c,
    int2* __restrict__ packed, int E) {
  int p = blockIdx.x * 256 + threadIdx.x;
  if (p >= E) return;
  int2 s = pstat[p];                     // sequential 8B
  float nrm = dinv[s.x] * wgr[s.y] * dinv[colof_c[p]];  // L2 tables
  int2 rec; rec.x = s.x; rec.y = __float_as_int(nrm);
  packed[p] = rec;                       // sequential 8B
}

// ---- GEMM: out_bf16[M,128] = A[M,128] @ W[128,128]; A fp32 or bf16 ---------
__global__ __launch_bounds__(256) void k_gemm128(const void* __restrict__ Av,
                                                 int a_bf16,
                                                 const float* __restrict__ W,
                                                 __hip_bfloat16* __restrict__ out, int M) {
  __shared__ float As[128][36];
  int t = threadIdx.x;
  int n0 = blockIdx.x * 32;
  for (int i = t; i < 32 * 128; i += 256) {
    int nn = i >> 7, kk = i & 127;
    int gn = n0 + nn;
    float v = 0.f;
    if (gn < M) {
      if (a_bf16) v = __bfloat162float(((const __hip_bfloat16*)Av)[(size_t)gn * 128 + kk]);
      else v = ((const float*)Av)[(size_t)gn * 128 + kk];
    }
    As[kk][nn] = v;
  }
  __syncthreads();
  int nb = (t >> 6) * 8;
  int j2 = (t & 63) * 2;
  float acc[8][2] = {};
  for (int k = 0; k < 128; ++k) {
    float4 a01 = *(const float4*)&As[k][nb];
    float4 a23 = *(const float4*)&As[k][nb + 4];
    float2 wv = *(const float2*)&W[k * 128 + j2];
    acc[0][0] += a01.x * wv.x; acc[0][1] += a01.x * wv.y;
    acc[1][0] += a01.y * wv.x; acc[1][1] += a01.y * wv.y;
    acc[2][0] += a01.z * wv.x; acc[2][1] += a01.z * wv.y;
    acc[3][0] += a01.w * wv.x; acc[3][1] += a01.w * wv.y;
    acc[4][0] += a23.x * wv.x; acc[4][1] += a23.x * wv.y;
    acc[5][0] += a23.y * wv.x; acc[5][1] += a23.y * wv.y;
    acc[6][0] += a23.z * wv.x; acc[6][1] += a23.z * wv.y;
    acc[7][0] += a23.w * wv.x; acc[7][1] += a23.w * wv.y;
  }
  __hip_bfloat162* o2 = (__hip_bfloat162*)out;
#pragma unroll
  for (int i = 0; i < 8; ++i) {
    int gn = n0 + nb + i;
    if (gn < M) {
      __hip_bfloat162 o;
      o.x = __float2bfloat16(acc[i][0]); o.y = __float2bfloat16(acc[i][1]);
      o2[(size_t)gn * 64 + (j2 >> 1)] = o;
    }
  }
}

// ---- GEMM: out_bf16[M,40] = A_bf16[M,128] @ W[128,40] ----------------------
__global__ __launch_bounds__(320) void k_gemm40(const __hip_bfloat16* __restrict__ A,
                                                const float* __restrict__ W,
                                                __hip_bfloat16* __restrict__ out,
                                                int M, int C) {
  __shared__ float As[128][68];
  int t = threadIdx.x;
  int n0 = blockIdx.x * 64;
  for (int i = t; i < 64 * 128; i += 320) {
    int nn = i >> 7, kk = i & 127;
    int gn = n0 + nn;
    As[kk][nn] = (gn < M) ? __bfloat162float(A[(size_t)gn * 128 + kk]) : 0.f;
  }
  __syncthreads();
  int gq = t / 40;
  int jc = t - gq * 40;
  int nb = gq * 8;
  float acc[8] = {};
  for (int k = 0; k < 128; ++k) {
    float4 a01 = *(const float4*)&As[k][nb];
    float4 a23 = *(const float4*)&As[k][nb + 4];
    float wv = W[k * C + jc];
    acc[0] += a01.x * wv; acc[1] += a01.y * wv; acc[2] += a01.z * wv; acc[3] += a01.w * wv;
    acc[4] += a23.x * wv; acc[5] += a23.y * wv; acc[6] += a23.z * wv; acc[7] += a23.w * wv;
  }
#pragma unroll
  for (int i = 0; i < 8; ++i) {
    int gn = n0 + nb + i;
    if (gn < M) out[(size_t)gn * C + jc] = __float2bfloat16(acc[i]);
  }
}

// ---- aggregation + bias + relu + row-normalize; nrm precomputed ------------
__global__ __launch_bounds__(256) void k_agg_norm(
    const __hip_bfloat162* __restrict__ hWb, const int2* __restrict__ packed,
    const int* __restrict__ offs_c, const float* __restrict__ bias,
    __hip_bfloat16* __restrict__ outb, float* __restrict__ xn,
    __hip_bfloat16* __restrict__ xnb, int N) {
  int w = threadIdx.x >> 6;
  int t = threadIdx.x & 63;
  int c = blockIdx.x * 4 + w;
  if (c >= N) return;
  int p0 = offs_c[c], p1 = offs_c[c + 1];
  float acc0 = bias[2 * t], acc1 = bias[2 * t + 1];
  int p = p0;
  for (; p + 8 <= p1; p += 8) {   // 8 row-gathers in flight
    int2 s[8];
    __hip_bfloat162 h[8];
#pragma unroll
    for (int k = 0; k < 8; ++k) s[k] = packed[p + k];
#pragma unroll
    for (int k = 0; k < 8; ++k) h[k] = hWb[(size_t)s[k].x * 64 + t];
#pragma unroll
    for (int k = 0; k < 8; ++k) {
      float n = __int_as_float(s[k].y);
      acc0 += n * __bfloat162float(h[k].x);
      acc1 += n * __bfloat162float(h[k].y);
    }
  }
  for (; p + 4 <= p1; p += 4) {
    int2 s0 = packed[p], s1 = packed[p + 1], s2 = packed[p + 2], s3 = packed[p + 3];
    __hip_bfloat162 h0 = hWb[(size_t)s0.x * 64 + t];
    __hip_bfloat162 h1 = hWb[(size_t)s1.x * 64 + t];
    __hip_bfloat162 h2 = hWb[(size_t)s2.x * 64 + t];
    __hip_bfloat162 h3 = hWb[(size_t)s3.x * 64 + t];
    float n0 = __int_as_float(s0.y), n1 = __int_as_float(s1.y);
    float n2 = __int_as_float(s2.y), n3 = __int_as_float(s3.y);
    acc0 += n0 * __bfloat162float(h0.x) + n1 * __bfloat162float(h1.x)
          + n2 * __bfloat162float(h2.x) + n3 * __bfloat162float(h3.x);
    acc1 += n0 * __bfloat162float(h0.y) + n1 * __bfloat162float(h1.y)
          + n2 * __bfloat162float(h2.y) + n3 * __bfloat162float(h3.y);
  }
  for (; p < p1; ++p) {
    int2 s0 = packed[p];
    __hip_bfloat162 h0 = hWb[(size_t)s0.x * 64 + t];
    float n0 = __int_as_float(s0.y);
    acc0 += n0 * __bfloat162float(h0.x);
    acc1 += n0 * __bfloat162float(h0.y);
  }
  acc0 = fmaxf(acc0, 0.f); acc1 = fmaxf(acc1, 0.f);
  __hip_bfloat162 oh;                    // h stored bf16 (GEMM input next layer)
  oh.x = __float2bfloat16(acc0); oh.y = __float2bfloat16(acc1);
  ((__hip_bfloat162*)outb)[(size_t)c * 64 + t] = oh;
  float ss = acc0 * acc0 + acc1 * acc1;
#pragma unroll
  for (int m = 32; m >= 1; m >>= 1) ss += __shfl_xor(ss, m);
  float inv = 1.0f / fmaxf(sqrtf(ss), 1e-12f);
  float2 on; on.x = acc0 * inv; on.y = acc1 * inv;
  ((float2*)xn)[(size_t)c * 64 + t] = on;
  __hip_bfloat162 ob;
  ob.x = __float2bfloat16(on.x); ob.y = __float2bfloat16(on.y);
  ((__hip_bfloat162*)xnb)[(size_t)c * 64 + t] = ob;
}

// ------- final aggregation + bias + log_softmax; nrm precomputed ------------
__global__ __launch_bounds__(256) void k_agg40_lsm(
    const __hip_bfloat16* __restrict__ hW, const int2* __restrict__ packed,
    const int* __restrict__ offs_c, const float* __restrict__ bias,
    float* __restrict__ out, int C, int N) {
  int w = threadIdx.x >> 6;
  int j = threadIdx.x & 63;
  int c = blockIdx.x * 4 + w;
  if (c >= N) return;
  int p0 = offs_c[c], p1 = offs_c[c + 1];
  bool act = j < C;
  int jj = act ? j : 0;
  float acc = act ? bias[jj] : 0.f;
  int p = p0;
  for (; p + 4 <= p1; p += 4) {
    int2 s0 = packed[p], s1 = packed[p + 1], s2 = packed[p + 2], s3 = packed[p + 3];
    float h0 = __bfloat162float(hW[(size_t)s0.x * C + jj]);
    float h1 = __bfloat162float(hW[(size_t)s1.x * C + jj]);
    float h2 = __bfloat162float(hW[(size_t)s2.x * C + jj]);
    float h3 = __bfloat162float(hW[(size_t)s3.x * C + jj]);
    acc += __int_as_float(s0.y) * h0 + __int_as_float(s1.y) * h1
         + __int_as_float(s2.y) * h2 + __int_as_float(s3.y) * h3;
  }
  for (; p < p1; ++p) {
    int2 s0 = packed[p];
    acc += __int_as_float(s0.y) * __bfloat162float(hW[(size_t)s0.x * C + jj]);
  }
  if (!act) acc = 0.f;
  float v = act ? acc : -3.0e38f;
#pragma unroll
  for (int m = 32; m >= 1; m >>= 1) v = fmaxf(v, __shfl_xor(v, m));
  float ex = act ? expf(acc - v) : 0.f;
#pragma unroll
  for (int m = 32; m >= 1; m >>= 1) ex += __shfl_xor(ex, m);
  if (act) out[(size_t)c * C + j] = acc - v - logf(ex);
}

extern "C" void kernel_launch(void* const* d_in, const int* in_sizes, int n_in,
                              void* d_out, int out_size, void* d_ws, size_t ws_size,
                              hipStream_t stream) {
  const float* x    = (const float*)d_in[0];
  const float* gate = (const float*)d_in[1];
  const float* W0   = (const float*)d_in[2];
  const float* b0   = (const float*)d_in[3];
  const float* W1   = (const float*)d_in[4];
  const float* b1   = (const float*)d_in[5];
  const float* W2   = (const float*)d_in[6];
  const float* b2   = (const float*)d_in[7];
  const int* eidx   = (const int*)d_in[8];
  int N = in_sizes[0] / 128;
  int E = in_sizes[8] / 2;
  int C = in_sizes[7];  // 40
  const int* row = eidx;
  const int* col = eidx + E;

  char* ws = (char*)d_ws;
  size_t off = 0;
  auto alloc = [&](size_t bytes) {
    char* p = ws + off;
    off += (bytes + 255) & ~(size_t)255;
    return p;
  };
  float* xn     = (float*)alloc((size_t)N * 128 * 4);
  __hip_bfloat16* xnb  = (__hip_bfloat16*)alloc((size_t)N * 128 * 2);
  __hip_bfloat16* bufC = (__hip_bfloat16*)alloc((size_t)N * 128 * 2);  // h, bf16
  __hip_bfloat16* hWb  = (__hip_bfloat16*)alloc((size_t)N * 128 * 2);
  float* adjr   = (float*)alloc((size_t)E * 4);    // layer-0 weights, row-CSR order
  float* wgr    = (float*)alloc((size_t)E * 4);    // gated weight, row-CSR order
  int*   perm_r = (int*)alloc((size_t)E * 4);
  int2*  pstat  = (int2*)alloc((size_t)E * 8);     // (row, rowCSR-slot) per col slot
  int2*  packed = (int2*)alloc((size_t)E * 8);     // (row, nrm) per col slot
  int*   colof_r= (int*)alloc((size_t)E * 4);
  int*   colof_c= (int*)alloc((size_t)E * 4);
  int*   ebuck  = (int*)alloc((size_t)E * 4);      // bucket-partitioned packed ids
  int*   offs_c = (int*)alloc((size_t)(N + 1) * 4);
  int*   offs_r = (int*)alloc((size_t)(N + 1) * 4);
  float* dinv   = (float*)alloc((size_t)N * 4);

  int NCHUNK = (E + 2047) / 2048;
  int M      = 256 * NCHUNK;
  int*   ghist  = (int*)alloc((size_t)M * 4);
  int*   partial= (int*)alloc((size_t)M * 4);
  int*   bsum   = (int*)alloc((size_t)NCHUNK * 4);
  int*   boffs  = (int*)alloc((size_t)NCHUNK * 4);

  int NBUK = (N + 255) / 256;
  int nb1  = (N + 255) / 256;
  int eb1  = (E + 255) / 256;
  int nw4  = (N + 3) / 4;

  // ---- CSR build: atomic-free two-level counting sort (row, then col) ----
  k_lhist<<<NCHUNK, 256, 0, stream>>>(row, nullptr, ghist, nullptr, NCHUNK, E);
  k_scan1<<<NCHUNK, 256, 0, stream>>>(ghist, partial, bsum, M);
  k_scan2<<<1, 256, 0, stream>>>(bsum, boffs, NCHUNK);
  k_bucketize<<<NCHUNK, 256, 0, stream>>>(row, nullptr, partial, boffs, ebuck, NCHUNK, E);
  k_final_row<<<NBUK, 256, 0, stream>>>(ebuck, partial, boffs, perm_r, offs_r,
                                        NCHUNK, N, E);
  k_lhist<<<NCHUNK, 256, 0, stream>>>(col, perm_r, ghist, colof_r, NCHUNK, E);
  k_scan1<<<NCHUNK, 256, 0, stream>>>(ghist, partial, bsum, M);
  k_scan2<<<1, 256, 0, stream>>>(bsum, boffs, NCHUNK);
  k_bucketize<<<NCHUNK, 256, 0, stream>>>(col, perm_r, partial, boffs, ebuck, NCHUNK, E);
  k_final_col<<<NBUK, 256, 0, stream>>>(ebuck, perm_r, row, partial, boffs, pstat,
                                        colof_c, offs_c, NCHUNK, N, E);

  for (int layer = 0; layer < 3; ++layer) {
    if (layer == 0) k_normalize<<<(N + 3) / 4, 256, 0, stream>>>(x, xn, xnb, N);
    k_simw<<<nw4, 256, 0, stream>>>(xn, xnb, colof_r, offs_r, adjr, wgr,
                                    gate, layer, N);
    k_colw<<<nb1, 256, 0, stream>>>(pstat, wgr, offs_c, dinv, N);
    k_nrm<<<eb1, 256, 0, stream>>>(pstat, wgr, dinv, colof_c, packed, E);
    if (layer < 2) {
      const float* W = (layer == 0) ? W0 : W1;
      const float* b = (layer == 0) ? b0 : b1;
      if (layer == 0)
        k_gemm128<<<(N + 31) / 32, 256, 0, stream>>>((const void*)x, 0, W, hWb, N);
      else
        k_gemm128<<<(N + 31) / 32, 256, 0, stream>>>((const void*)bufC, 1, W, hWb, N);
      k_agg_norm<<<nw4, 256, 0, stream>>>((const __hip_bfloat162*)hWb, packed, offs_c,
                                          b, bufC, xn, xnb, N);
    } else {
      k_gemm40<<<(N + 63) / 64, 320, 0, stream>>>(bufC, W2, hWb, N, C);
      k_agg40_lsm<<<nw4, 256, 0, stream>>>(hWb, packed, offs_c, b2, (float*)d_out, C, N);
    }
  }
}

// Round 15
// 591.439 us; speedup vs baseline: 1.0387x; 1.0167x over previous
//
#include <hip/hip_runtime.h>
#include <hip/hip_bf16.h>
#include <math.h>

#define F 128

typedef __attribute__((ext_vector_type(8))) short bf16x8;
typedef __attribute__((ext_vector_type(4))) float f32x4;

// ------- row-normalize: xn = x/max(||x||,eps) (fp32 + bf16 copies) ----------
__global__ void k_normalize(const float* __restrict__ x, float* __restrict__ xn,
                            __hip_bfloat16* __restrict__ xnb, int N) {
  int wid = (blockIdx.x * blockDim.x + threadIdx.x) >> 6;  // one wave per node
  int lane = threadIdx.x & 63;
  if (wid >= N) return;
  const float2* src = (const float2*)(x + (size_t)wid * F);
  float2 v = src[lane];
  float ss = v.x * v.x + v.y * v.y;
#pragma unroll
  for (int m = 32; m >= 1; m >>= 1) ss += __shfl_xor(ss, m);
  float inv = 1.0f / fmaxf(sqrtf(ss), 1e-12f);
  float2 o; o.x = v.x * inv; o.y = v.y * inv;
  ((float2*)(xn + (size_t)wid * F))[lane] = o;
  __hip_bfloat162 ob;
  ob.x = __float2bfloat16(o.x); ob.y = __float2bfloat16(o.y);
  ((__hip_bfloat162*)(xnb + (size_t)wid * F))[lane] = ob;
}

// ============ CSR build: atomic-free two-level LDS counting sort ============
__global__ __launch_bounds__(256) void k_lhist(
    const int* __restrict__ keys, const int* __restrict__ perm,
    int* __restrict__ ghist, int* __restrict__ keyout, int nchunk, int E) {
  __shared__ int lh[256];
  int t = threadIdx.x, chunk = blockIdx.x;
  lh[t] = 0;
  __syncthreads();
  int base = chunk * 2048;
#pragma unroll
  for (int k = 0; k < 8; ++k) {
    int i = base + k * 256 + t;
    if (i < E) {
      int key = perm ? keys[perm[i]] : keys[i];
      if (keyout) keyout[i] = key;
      atomicAdd(&lh[key >> 8], 1);
    }
  }
  __syncthreads();
  ghist[t * nchunk + chunk] = lh[t];
}

__global__ void k_scan1(const int* __restrict__ cnt, int* __restrict__ partial,
                        int* __restrict__ bsum, int M) {
  __shared__ int sm[256];
  int t = threadIdx.x;
  int i = blockIdx.x * 256 + t;
  int val = (i < M) ? cnt[i] : 0;
  sm[t] = val;
  __syncthreads();
  for (int off = 1; off < 256; off <<= 1) {
    int v = (t >= off) ? sm[t - off] : 0;
    __syncthreads();
    sm[t] += v;
    __syncthreads();
  }
  if (i < M) partial[i] = sm[t] - val;  // exclusive
  if (t == 255) bsum[blockIdx.x] = sm[255];
}

__global__ void k_scan2(const int* __restrict__ bsum, int* __restrict__ boffs, int nb) {
  __shared__ int sm[256];
  int t = threadIdx.x;
  int carry = 0;
  for (int base = 0; base < nb; base += 256) {
    int idx = base + t;
    int val = (idx < nb) ? bsum[idx] : 0;
    sm[t] = val;
    __syncthreads();
    for (int off = 1; off < 256; off <<= 1) {
      int v = (t >= off) ? sm[t - off] : 0;
      __syncthreads();
      sm[t] += v;
      __syncthreads();
    }
    if (idx < nb) boffs[idx] = sm[t] - val + carry;
    carry += sm[255];
    __syncthreads();
  }
}

__global__ __launch_bounds__(256) void k_bucketize(
    const int* __restrict__ keys, const int* __restrict__ perm,
    const int* __restrict__ partial, const int* __restrict__ boffs,
    int* __restrict__ ebuck, int nchunk, int E) {
  __shared__ int lcur[256];
  int t = threadIdx.x, chunk = blockIdx.x;
  int idx = t * nchunk + chunk;
  lcur[t] = partial[idx] + boffs[idx >> 8];
  __syncthreads();
  int base = chunk * 2048;
#pragma unroll
  for (int k = 0; k < 8; ++k) {
    int i = base + k * 256 + t;
    if (i < E) {
      int key = perm ? keys[perm[i]] : keys[i];
      int pos = atomicAdd(&lcur[key >> 8], 1);
      ebuck[pos] = (i << 8) | (key & 255);
    }
  }
}

__global__ __launch_bounds__(256) void k_final_row(
    const int* __restrict__ ebuck, const int* __restrict__ partial,
    const int* __restrict__ boffs, int* __restrict__ perm_r,
    int* __restrict__ offs_r, int nchunk, int N, int E) {
  __shared__ int lh[256], sm[256], lscan[256];
  int t = threadIdx.x, b = blockIdx.x;
  int i0 = b * nchunk;
  int start = partial[i0] + boffs[i0 >> 8];
  int i1 = i0 + nchunk;
  int end = (b < 255) ? partial[i1] + boffs[i1 >> 8] : E;
  lh[t] = 0;
  __syncthreads();
  for (int p = start + t; p < end; p += 256) atomicAdd(&lh[ebuck[p] & 255], 1);
  __syncthreads();
  int val = lh[t];
  sm[t] = val;
  __syncthreads();
  for (int off = 1; off < 256; off <<= 1) {
    int v = (t >= off) ? sm[t - off] : 0;
    __syncthreads();
    sm[t] += v;
    __syncthreads();
  }
  lscan[t] = sm[t] - val;
  int node = b * 256 + t;
  if (node < N) offs_r[node] = start + lscan[t];
  if (b == 0 && t == 0) offs_r[N] = E;
  lh[t] = 0;
  __syncthreads();
  for (int p = start + t; p < end; p += 256) {
    int v = ebuck[p];
    int low = v & 255;
    int rk = atomicAdd(&lh[low], 1);
    perm_r[start + lscan[low] + rk] = v >> 8;
  }
}

// per-bucket finalize (col): emits pstat[pc]=(row,rowCSR-slot) and colof_c[pc]
__global__ __launch_bounds__(256) void k_final_col(
    const int* __restrict__ ebuck, const int* __restrict__ perm_r,
    const int* __restrict__ row, const int* __restrict__ partial,
    const int* __restrict__ boffs, int2* __restrict__ pstat,
    int* __restrict__ colof_c, int* __restrict__ offs_c, int nchunk, int N, int E) {
  __shared__ int lh[256], sm[256], lscan[256];
  int t = threadIdx.x, b = blockIdx.x;
  int i0 = b * nchunk;
  int start = partial[i0] + boffs[i0 >> 8];
  int i1 = i0 + nchunk;
  int end = (b < 255) ? partial[i1] + boffs[i1 >> 8] : E;
  lh[t] = 0;
  __syncthreads();
  for (int p = start + t; p < end; p += 256) atomicAdd(&lh[ebuck[p] & 255], 1);
  __syncthreads();
  int val = lh[t];
  sm[t] = val;
  __syncthreads();
  for (int off = 1; off < 256; off <<= 1) {
    int v = (t >= off) ? sm[t - off] : 0;
    __syncthreads();
    sm[t] += v;
    __syncthreads();
  }
  lscan[t] = sm[t] - val;
  int node = b * 256 + t;
  if (node < N) offs_c[node] = start + lscan[t];
  if (b == 0 && t == 0) offs_c[N] = E;
  lh[t] = 0;
  __syncthreads();
  for (int p = start + t; p < end; p += 256) {
    int v = ebuck[p];
    int low = v & 255;
    int rp = v >> 8;                      // rowCSR slot (~ascending -> L2 locality)
    int e = perm_r[rp];
    int rk = atomicAdd(&lh[low], 1);
    int pos = start + lscan[low] + rk;
    int2 rec; rec.x = row[e]; rec.y = rp;
    pstat[pos] = rec;
    colof_c[pos] = b * 256 + low;
  }
}

// ------- fused per-row sims + weights, MFMA edition. One wave per row. ------
// R13-measured best: no pipelining (VGPR 24, occ ~64%, 47 us). R14's 2-stage
// prefetch regressed (VGPR 40, occ 47%) — TLP already covers gather latency.
__global__ __launch_bounds__(256) void k_simw(
    const float* __restrict__ xn, const __hip_bfloat16* __restrict__ xnb,
    const int* __restrict__ colof_r, const int* __restrict__ offs_r,
    float* __restrict__ adjr, float* __restrict__ wgr,
    const float* __restrict__ gate, int layer, int N) {
  int w = threadIdx.x >> 6;   // wave 0..3, one row each
  int l = threadIdx.x & 63;
  int r = blockIdx.x * 4 + w;
  __shared__ float sims[4][320];
  __shared__ int scol[4][320];
  if (r >= N) return;
  int p0 = offs_r[r], p1 = offs_r[r + 1];
  int ne = p1 - p0;                     // ~17 (Poisson(16) + self loop), <320
  int quad = l >> 4;
  int m = l & 15;
  int qoff = quad * 8;
  const __hip_bfloat16* xr = xnb + (size_t)r * F;
  bf16x8 b0 = *(const bf16x8*)(xr + 0 * 32 + qoff);   // 16-lane broadcast loads
  bf16x8 b1 = *(const bf16x8*)(xr + 1 * 32 + qoff);
  bf16x8 b2 = *(const bf16x8*)(xr + 2 * 32 + qoff);
  bf16x8 b3 = *(const bf16x8*)(xr + 3 * 32 + qoff);
  for (int tb = 0; tb < ne; tb += 16) {
    int ii = tb + m; if (ii > ne - 1) ii = ne - 1;     // clamp (extra rows ignored)
    int cm = colof_r[p0 + ii];
    if (quad == 0 && tb + m < ne) scol[w][tb + m] = cm;
    const __hip_bfloat16* xc = xnb + (size_t)cm * F;
    bf16x8 a0 = *(const bf16x8*)(xc + 0 * 32 + qoff);  // 4 independent 16B gathers
    bf16x8 a1 = *(const bf16x8*)(xc + 1 * 32 + qoff);
    bf16x8 a2 = *(const bf16x8*)(xc + 2 * 32 + qoff);
    bf16x8 a3 = *(const bf16x8*)(xc + 3 * 32 + qoff);
    f32x4 acc = {0.f, 0.f, 0.f, 0.f};
    acc = __builtin_amdgcn_mfma_f32_16x16x32_bf16(a0, b0, acc, 0, 0, 0);
    acc = __builtin_amdgcn_mfma_f32_16x16x32_bf16(a1, b1, acc, 0, 0, 0);
    acc = __builtin_amdgcn_mfma_f32_16x16x32_bf16(a2, b2, acc, 0, 0, 0);
    acc = __builtin_amdgcn_mfma_f32_16x16x32_bf16(a3, b3, acc, 0, 0, 0);
    if (m == 0) {                       // lanes 0,16,32,48 hold rows quad*4+reg
#pragma unroll
      for (int reg = 0; reg < 4; ++reg) {
        int i = tb + quad * 4 + reg;
        if (i < ne) sims[w][i] = acc[reg];
      }
    }
  }
  // pass 2: guard-band fp32 recompute + threshold + rowsum/deg (one wave).
  // Band: bf16 rounding 2^-8/operand -> dot err <= 2^-7 = 0.0078 worst case
  // (Cauchy-Schwarz, unit vectors); +-0.01 covers it deterministically.
  float vsum = 0.f; int cn = 0;
  for (int base = 0; base < ne; base += 64) {
    int i = base + l;
    bool have = i < ne;
    float s = have ? sims[w][i] : 0.f;
    int c = have ? scol[w][i] : r;
    bool self = (c == r);
    bool flag = have && !self && fabsf(s - 0.1f) < 0.01f;
    unsigned long long mask = __ballot(flag);
    while (mask) {                      // ~0.8 flagged edge/row: wave-coop fp32 dot
      int src = __ffsll(mask) - 1;
      mask &= mask - 1;
      int cc = __shfl(c, src);
      float2 ar = ((const float2*)(xn + (size_t)r * F))[l];
      float2 bc = ((const float2*)(xn + (size_t)cc * F))[l];
      float d = ar.x * bc.x + ar.y * bc.y;
#pragma unroll
      for (int mm = 32; mm >= 1; mm >>= 1) d += __shfl_xor(d, mm);
      if (l == src) s = d;
    }
    if (self || s < 0.1f) s = 0.f;
    if (have) sims[w][i] = s;
    vsum += s;
    cn += (s > 0.f) ? 1 : 0;
  }
#pragma unroll
  for (int mm = 32; mm >= 1; mm >>= 1) {
    vsum += __shfl_xor(vsum, mm);
    cn += __shfl_xor(cn, mm);
  }
  float rs = vsum;
  float lam = 1.0f / (float)(cn + 1);
  float gg = (layer > 0) ? gate[layer - 1] : 0.f;
  for (int i = l; i < ne; i += 64) {
    int c = scol[w][i];
    float s = sims[w][i];
    float sn = (rs > 0.f) ? s / rs : 0.f;
    float wv = (c == r) ? lam : sn;
    wv = expf(wv);                      // thresholded edges get exp(0)=1
    float wc;
    if (layer == 0) { adjr[p0 + i] = wv; wc = wv; }
    else { wc = gg * adjr[p0 + i] + (1.f - gg) * wv; }
    wgr[p0 + i] = wc;                   // sequential write; NO atomics
  }
}

// ---- dinv[c] = rsqrt(sum of wc over col segment); no atomics ---------------
__global__ __launch_bounds__(256) void k_colw(
    const int2* __restrict__ pstat, const float* __restrict__ wgr,
    const int* __restrict__ offs_c, float* __restrict__ dinv, int N) {
  int c = blockIdx.x * 256 + threadIdx.x;
  if (c >= N) return;
  int p0 = offs_c[c], p1 = offs_c[c + 1];
  float s = 0.f;
  int p = p0;
  for (; p + 4 <= p1; p += 4) {        // 4 random L2 reads in flight
    int2 a = pstat[p], b = pstat[p + 1], d = pstat[p + 2], e = pstat[p + 3];
    s += wgr[a.y] + wgr[b.y] + wgr[d.y] + wgr[e.y];
  }
  for (; p < p1; ++p) s += wgr[pstat[p].y];
  dinv[c] = (s > 0.f) ? rsqrtf(s) : 0.f;
}

// ---- packed[p] = (row, dinv[r]*w*dinv[c]); EDGE-parallel, all loads indep --
__global__ __launch_bounds__(256) void k_nrm(
    const int2* __restrict__ pstat, const float* __restrict__ wgr,
    const float* __restrict__ dinv, const int* __restrict__ colof_c,
    int2* __restrict__ packed, int E) {
  int p = blockIdx.x * 256 + threadIdx.x;
  if (p >= E) return;
  int2 s = pstat[p];                     // sequential 8B
  float nrm = dinv[s.x] * wgr[s.y] * dinv[colof_c[p]];  // L2 tables
  int2 rec; rec.x = s.x; rec.y = __float_as_int(nrm);
  packed[p] = rec;                       // sequential 8B
}

// ---- GEMM: out_bf16[M,128] = A[M,128] @ W[128,128]; A fp32 or bf16 ---------
__global__ __launch_bounds__(256) void k_gemm128(const void* __restrict__ Av,
                                                 int a_bf16,
                                                 const float* __restrict__ W,
                                                 __hip_bfloat16* __restrict__ out, int M) {
  __shared__ float As[128][36];
  int t = threadIdx.x;
  int n0 = blockIdx.x * 32;
  for (int i = t; i < 32 * 128; i += 256) {
    int nn = i >> 7, kk = i & 127;
    int gn = n0 + nn;
    float v = 0.f;
    if (gn < M) {
      if (a_bf16) v = __bfloat162float(((const __hip_bfloat16*)Av)[(size_t)gn * 128 + kk]);
      else v = ((const float*)Av)[(size_t)gn * 128 + kk];
    }
    As[kk][nn] = v;
  }
  __syncthreads();
  int nb = (t >> 6) * 8;
  int j2 = (t & 63) * 2;
  float acc[8][2] = {};
  for (int k = 0; k < 128; ++k) {
    float4 a01 = *(const float4*)&As[k][nb];
    float4 a23 = *(const float4*)&As[k][nb + 4];
    float2 wv = *(const float2*)&W[k * 128 + j2];
    acc[0][0] += a01.x * wv.x; acc[0][1] += a01.x * wv.y;
    acc[1][0] += a01.y * wv.x; acc[1][1] += a01.y * wv.y;
    acc[2][0] += a01.z * wv.x; acc[2][1] += a01.z * wv.y;
    acc[3][0] += a01.w * wv.x; acc[3][1] += a01.w * wv.y;
    acc[4][0] += a23.x * wv.x; acc[4][1] += a23.x * wv.y;
    acc[5][0] += a23.y * wv.x; acc[5][1] += a23.y * wv.y;
    acc[6][0] += a23.z * wv.x; acc[6][1] += a23.z * wv.y;
    acc[7][0] += a23.w * wv.x; acc[7][1] += a23.w * wv.y;
  }
  __hip_bfloat162* o2 = (__hip_bfloat162*)out;
#pragma unroll
  for (int i = 0; i < 8; ++i) {
    int gn = n0 + nb + i;
    if (gn < M) {
      __hip_bfloat162 o;
      o.x = __float2bfloat16(acc[i][0]); o.y = __float2bfloat16(acc[i][1]);
      o2[(size_t)gn * 64 + (j2 >> 1)] = o;
    }
  }
}

// ---- GEMM: out_bf16[M,40] = A_bf16[M,128] @ W[128,40] ----------------------
__global__ __launch_bounds__(320) void k_gemm40(const __hip_bfloat16* __restrict__ A,
                                                const float* __restrict__ W,
                                                __hip_bfloat16* __restrict__ out,
                                                int M, int C) {
  __shared__ float As[128][68];
  int t = threadIdx.x;
  int n0 = blockIdx.x * 64;
  for (int i = t; i < 64 * 128; i += 320) {
    int nn = i >> 7, kk = i & 127;
    int gn = n0 + nn;
    As[kk][nn] = (gn < M) ? __bfloat162float(A[(size_t)gn * 128 + kk]) : 0.f;
  }
  __syncthreads();
  int gq = t / 40;
  int jc = t - gq * 40;
  int nb = gq * 8;
  float acc[8] = {};
  for (int k = 0; k < 128; ++k) {
    float4 a01 = *(const float4*)&As[k][nb];
    float4 a23 = *(const float4*)&As[k][nb + 4];
    float wv = W[k * C + jc];
    acc[0] += a01.x * wv; acc[1] += a01.y * wv; acc[2] += a01.z * wv; acc[3] += a01.w * wv;
    acc[4] += a23.x * wv; acc[5] += a23.y * wv; acc[6] += a23.z * wv; acc[7] += a23.w * wv;
  }
#pragma unroll
  for (int i = 0; i < 8; ++i) {
    int gn = n0 + nb + i;
    if (gn < M) out[(size_t)gn * C + jc] = __float2bfloat16(acc[i]);
  }
}

// ---- aggregation + bias + relu + row-normalize; nrm precomputed ------------
__global__ __launch_bounds__(256) void k_agg_norm(
    const __hip_bfloat162* __restrict__ hWb, const int2* __restrict__ packed,
    const int* __restrict__ offs_c, const float* __restrict__ bias,
    __hip_bfloat16* __restrict__ outb, float* __restrict__ xn,
    __hip_bfloat16* __restrict__ xnb, int N) {
  int w = threadIdx.x >> 6;
  int t = threadIdx.x & 63;
  int c = blockIdx.x * 4 + w;
  if (c >= N) return;
  int p0 = offs_c[c], p1 = offs_c[c + 1];
  float acc0 = bias[2 * t], acc1 = bias[2 * t + 1];
  int p = p0;
  for (; p + 8 <= p1; p += 8) {   // 8 row-gathers in flight
    int2 s[8];
    __hip_bfloat162 h[8];
#pragma unroll
    for (int k = 0; k < 8; ++k) s[k] = packed[p + k];
#pragma unroll
    for (int k = 0; k < 8; ++k) h[k] = hWb[(size_t)s[k].x * 64 + t];
#pragma unroll
    for (int k = 0; k < 8; ++k) {
      float n = __int_as_float(s[k].y);
      acc0 += n * __bfloat162float(h[k].x);
      acc1 += n * __bfloat162float(h[k].y);
    }
  }
  for (; p + 4 <= p1; p += 4) {
    int2 s0 = packed[p], s1 = packed[p + 1], s2 = packed[p + 2], s3 = packed[p + 3];
    __hip_bfloat162 h0 = hWb[(size_t)s0.x * 64 + t];
    __hip_bfloat162 h1 = hWb[(size_t)s1.x * 64 + t];
    __hip_bfloat162 h2 = hWb[(size_t)s2.x * 64 + t];
    __hip_bfloat162 h3 = hWb[(size_t)s3.x * 64 + t];
    float n0 = __int_as_float(s0.y), n1 = __int_as_float(s1.y);
    float n2 = __int_as_float(s2.y), n3 = __int_as_float(s3.y);
    acc0 += n0 * __bfloat162float(h0.x) + n1 * __bfloat162float(h1.x)
          + n2 * __bfloat162float(h2.x) + n3 * __bfloat162float(h3.x);
    acc1 += n0 * __bfloat162float(h0.y) + n1 * __bfloat162float(h1.y)
          + n2 * __bfloat162float(h2.y) + n3 * __bfloat162float(h3.y);
  }
  for (; p < p1; ++p) {
    int2 s0 = packed[p];
    __hip_bfloat162 h0 = hWb[(size_t)s0.x * 64 + t];
    float n0 = __int_as_float(s0.y);
    acc0 += n0 * __bfloat162float(h0.x);
    acc1 += n0 * __bfloat162float(h0.y);
  }
  acc0 = fmaxf(acc0, 0.f); acc1 = fmaxf(acc1, 0.f);
  __hip_bfloat162 oh;                    // h stored bf16 (GEMM input next layer)
  oh.x = __float2bfloat16(acc0); oh.y = __float2bfloat16(acc1);
  ((__hip_bfloat162*)outb)[(size_t)c * 64 + t] = oh;
  float ss = acc0 * acc0 + acc1 * acc1;
#pragma unroll
  for (int m = 32; m >= 1; m >>= 1) ss += __shfl_xor(ss, m);
  float inv = 1.0f / fmaxf(sqrtf(ss), 1e-12f);
  float2 on; on.x = acc0 * inv; on.y = acc1 * inv;
  ((float2*)xn)[(size_t)c * 64 + t] = on;
  __hip_bfloat162 ob;
  ob.x = __float2bfloat16(on.x); ob.y = __float2bfloat16(on.y);
  ((__hip_bfloat162*)xnb)[(size_t)c * 64 + t] = ob;
}

// ------- final aggregation + bias + log_softmax; nrm precomputed ------------
__global__ __launch_bounds__(256) void k_agg40_lsm(
    const __hip_bfloat16* __restrict__ hW, const int2* __restrict__ packed,
    const int* __restrict__ offs_c, const float* __restrict__ bias,
    float* __restrict__ out, int C, int N) {
  int w = threadIdx.x >> 6;
  int j = threadIdx.x & 63;
  int c = blockIdx.x * 4 + w;
  if (c >= N) return;
  int p0 = offs_c[c], p1 = offs_c[c + 1];
  bool act = j < C;
  int jj = act ? j : 0;
  float acc = act ? bias[jj] : 0.f;
  int p = p0;
  for (; p + 4 <= p1; p += 4) {
    int2 s0 = packed[p], s1 = packed[p + 1], s2 = packed[p + 2], s3 = packed[p + 3];
    float h0 = __bfloat162float(hW[(size_t)s0.x * C + jj]);
    float h1 = __bfloat162float(hW[(size_t)s1.x * C + jj]);
    float h2 = __bfloat162float(hW[(size_t)s2.x * C + jj]);
    float h3 = __bfloat162float(hW[(size_t)s3.x * C + jj]);
    acc += __int_as_float(s0.y) * h0 + __int_as_float(s1.y) * h1
         + __int_as_float(s2.y) * h2 + __int_as_float(s3.y) * h3;
  }
  for (; p < p1; ++p) {
    int2 s0 = packed[p];
    acc += __int_as_float(s0.y) * __bfloat162float(hW[(size_t)s0.x * C + jj]);
  }
  if (!act) acc = 0.f;
  float v = act ? acc : -3.0e38f;
#pragma unroll
  for (int m = 32; m >= 1; m >>= 1) v = fmaxf(v, __shfl_xor(v, m));
  float ex = act ? expf(acc - v) : 0.f;
#pragma unroll
  for (int m = 32; m >= 1; m >>= 1) ex += __shfl_xor(ex, m);
  if (act) out[(size_t)c * C + j] = acc - v - logf(ex);
}

extern "C" void kernel_launch(void* const* d_in, const int* in_sizes, int n_in,
                              void* d_out, int out_size, void* d_ws, size_t ws_size,
                              hipStream_t stream) {
  const float* x    = (const float*)d_in[0];
  const float* gate = (const float*)d_in[1];
  const float* W0   = (const float*)d_in[2];
  const float* b0   = (const float*)d_in[3];
  const float* W1   = (const float*)d_in[4];
  const float* b1   = (const float*)d_in[5];
  const float* W2   = (const float*)d_in[6];
  const float* b2   = (const float*)d_in[7];
  const int* eidx   = (const int*)d_in[8];
  int N = in_sizes[0] / 128;
  int E = in_sizes[8] / 2;
  int C = in_sizes[7];  // 40
  const int* row = eidx;
  const int* col = eidx + E;

  char* ws = (char*)d_ws;
  size_t off = 0;
  auto alloc = [&](size_t bytes) {
    char* p = ws + off;
    off += (bytes + 255) & ~(size_t)255;
    return p;
  };
  float* xn     = (float*)alloc((size_t)N * 128 * 4);
  __hip_bfloat16* xnb  = (__hip_bfloat16*)alloc((size_t)N * 128 * 2);
  __hip_bfloat16* bufC = (__hip_bfloat16*)alloc((size_t)N * 128 * 2);  // h, bf16
  __hip_bfloat16* hWb  = (__hip_bfloat16*)alloc((size_t)N * 128 * 2);
  float* adjr   = (float*)alloc((size_t)E * 4);    // layer-0 weights, row-CSR order
  float* wgr    = (float*)alloc((size_t)E * 4);    // gated weight, row-CSR order
  int*   perm_r = (int*)alloc((size_t)E * 4);
  int2*  pstat  = (int2*)alloc((size_t)E * 8);     // (row, rowCSR-slot) per col slot
  int2*  packed = (int2*)alloc((size_t)E * 8);     // (row, nrm) per col slot
  int*   colof_r= (int*)alloc((size_t)E * 4);
  int*   colof_c= (int*)alloc((size_t)E * 4);
  int*   ebuck  = (int*)alloc((size_t)E * 4);      // bucket-partitioned packed ids
  int*   offs_c = (int*)alloc((size_t)(N + 1) * 4);
  int*   offs_r = (int*)alloc((size_t)(N + 1) * 4);
  float* dinv   = (float*)alloc((size_t)N * 4);

  int NCHUNK = (E + 2047) / 2048;
  int M      = 256 * NCHUNK;
  int*   ghist  = (int*)alloc((size_t)M * 4);
  int*   partial= (int*)alloc((size_t)M * 4);
  int*   bsum   = (int*)alloc((size_t)NCHUNK * 4);
  int*   boffs  = (int*)alloc((size_t)NCHUNK * 4);

  int NBUK = (N + 255) / 256;
  int nb1  = (N + 255) / 256;
  int eb1  = (E + 255) / 256;
  int nw4  = (N + 3) / 4;

  // ---- CSR build: atomic-free two-level counting sort (row, then col) ----
  k_lhist<<<NCHUNK, 256, 0, stream>>>(row, nullptr, ghist, nullptr, NCHUNK, E);
  k_scan1<<<NCHUNK, 256, 0, stream>>>(ghist, partial, bsum, M);
  k_scan2<<<1, 256, 0, stream>>>(bsum, boffs, NCHUNK);
  k_bucketize<<<NCHUNK, 256, 0, stream>>>(row, nullptr, partial, boffs, ebuck, NCHUNK, E);
  k_final_row<<<NBUK, 256, 0, stream>>>(ebuck, partial, boffs, perm_r, offs_r,
                                        NCHUNK, N, E);
  k_lhist<<<NCHUNK, 256, 0, stream>>>(col, perm_r, ghist, colof_r, NCHUNK, E);
  k_scan1<<<NCHUNK, 256, 0, stream>>>(ghist, partial, bsum, M);
  k_scan2<<<1, 256, 0, stream>>>(bsum, boffs, NCHUNK);
  k_bucketize<<<NCHUNK, 256, 0, stream>>>(col, perm_r, partial, boffs, ebuck, NCHUNK, E);
  k_final_col<<<NBUK, 256, 0, stream>>>(ebuck, perm_r, row, partial, boffs, pstat,
                                        colof_c, offs_c, NCHUNK, N, E);

  for (int layer = 0; layer < 3; ++layer) {
    if (layer == 0) k_normalize<<<(N + 3) / 4, 256, 0, stream>>>(x, xn, xnb, N);
    k_simw<<<nw4, 256, 0, stream>>>(xn, xnb, colof_r, offs_r, adjr, wgr,
                                    gate, layer, N);
    k_colw<<<nb1, 256, 0, stream>>>(pstat, wgr, offs_c, dinv, N);
    k_nrm<<<eb1, 256, 0, stream>>>(pstat, wgr, dinv, colof_c, packed, E);
    if (layer < 2) {
      const float* W = (layer == 0) ? W0 : W1;
      const float* b = (layer == 0) ? b0 : b1;
      if (layer == 0)
        k_gemm128<<<(N + 31) / 32, 256, 0, stream>>>((const void*)x, 0, W, hWb, N);
      else
        k_gemm128<<<(N + 31) / 32, 256, 0, stream>>>((const void*)bufC, 1, W, hWb, N);
      k_agg_norm<<<nw4, 256, 0, stream>>>((const __hip_bfloat162*)hWb, packed, offs_c,
                                          b, bufC, xn, xnb, N);
    } else {
      k_gemm40<<<(N + 63) / 64, 320, 0, stream>>>(bufC, W2, hWb, N, C);
      k_agg40_lsm<<<nw4, 256, 0, stream>>>(hWb, packed, offs_c, b2, (float*)d_out, C, N);
    }
  }
}

// Round 16
// 590.105 us; speedup vs baseline: 1.0411x; 1.0023x over previous
//
#include <hip/hip_runtime.h>
#include <hip/hip_bf16.h>
#include <math.h>

#define F 128

typedef __attribute__((ext_vector_type(8))) short bf16x8;
typedef __attribute__((ext_vector_type(4))) float f32x4;

// ------- row-normalize: xn = x/max(||x||,eps) (fp32 + bf16 copies) ----------
__global__ void k_normalize(const float* __restrict__ x, float* __restrict__ xn,
                            __hip_bfloat16* __restrict__ xnb, int N) {
  int wid = (blockIdx.x * blockDim.x + threadIdx.x) >> 6;  // one wave per node
  int lane = threadIdx.x & 63;
  if (wid >= N) return;
  const float2* src = (const float2*)(x + (size_t)wid * F);
  float2 v = src[lane];
  float ss = v.x * v.x + v.y * v.y;
#pragma unroll
  for (int m = 32; m >= 1; m >>= 1) ss += __shfl_xor(ss, m);
  float inv = 1.0f / fmaxf(sqrtf(ss), 1e-12f);
  float2 o; o.x = v.x * inv; o.y = v.y * inv;
  ((float2*)(xn + (size_t)wid * F))[lane] = o;
  __hip_bfloat162 ob;
  ob.x = __float2bfloat16(o.x); ob.y = __float2bfloat16(o.y);
  ((__hip_bfloat162*)(xnb + (size_t)wid * F))[lane] = ob;
}

// ============ CSR build: atomic-free two-level LDS counting sort ============
__global__ __launch_bounds__(256) void k_lhist(
    const int* __restrict__ keys, const int* __restrict__ perm,
    int* __restrict__ ghist, int* __restrict__ keyout, int nchunk, int E) {
  __shared__ int lh[256];
  int t = threadIdx.x, chunk = blockIdx.x;
  lh[t] = 0;
  __syncthreads();
  int base = chunk * 2048;
#pragma unroll
  for (int k = 0; k < 8; ++k) {
    int i = base + k * 256 + t;
    if (i < E) {
      int key = perm ? keys[perm[i]] : keys[i];
      if (keyout) keyout[i] = key;
      atomicAdd(&lh[key >> 8], 1);
    }
  }
  __syncthreads();
  ghist[t * nchunk + chunk] = lh[t];
}

__global__ void k_scan1(const int* __restrict__ cnt, int* __restrict__ partial,
                        int* __restrict__ bsum, int M) {
  __shared__ int sm[256];
  int t = threadIdx.x;
  int i = blockIdx.x * 256 + t;
  int val = (i < M) ? cnt[i] : 0;
  sm[t] = val;
  __syncthreads();
  for (int off = 1; off < 256; off <<= 1) {
    int v = (t >= off) ? sm[t - off] : 0;
    __syncthreads();
    sm[t] += v;
    __syncthreads();
  }
  if (i < M) partial[i] = sm[t] - val;  // exclusive
  if (t == 255) bsum[blockIdx.x] = sm[255];
}

__global__ void k_scan2(const int* __restrict__ bsum, int* __restrict__ boffs, int nb) {
  __shared__ int sm[256];
  int t = threadIdx.x;
  int carry = 0;
  for (int base = 0; base < nb; base += 256) {
    int idx = base + t;
    int val = (idx < nb) ? bsum[idx] : 0;
    sm[t] = val;
    __syncthreads();
    for (int off = 1; off < 256; off <<= 1) {
      int v = (t >= off) ? sm[t - off] : 0;
      __syncthreads();
      sm[t] += v;
      __syncthreads();
    }
    if (idx < nb) boffs[idx] = sm[t] - val + carry;
    carry += sm[255];
    __syncthreads();
  }
}

__global__ __launch_bounds__(256) void k_bucketize(
    const int* __restrict__ keys, const int* __restrict__ perm,
    const int* __restrict__ partial, const int* __restrict__ boffs,
    int* __restrict__ ebuck, int nchunk, int E) {
  __shared__ int lcur[256];
  int t = threadIdx.x, chunk = blockIdx.x;
  int idx = t * nchunk + chunk;
  lcur[t] = partial[idx] + boffs[idx >> 8];
  __syncthreads();
  int base = chunk * 2048;
#pragma unroll
  for (int k = 0; k < 8; ++k) {
    int i = base + k * 256 + t;
    if (i < E) {
      int key = perm ? keys[perm[i]] : keys[i];
      int pos = atomicAdd(&lcur[key >> 8], 1);
      ebuck[pos] = (i << 8) | (key & 255);
    }
  }
}

__global__ __launch_bounds__(256) void k_final_row(
    const int* __restrict__ ebuck, const int* __restrict__ partial,
    const int* __restrict__ boffs, int* __restrict__ perm_r,
    int* __restrict__ offs_r, int nchunk, int N, int E) {
  __shared__ int lh[256], sm[256], lscan[256];
  int t = threadIdx.x, b = blockIdx.x;
  int i0 = b * nchunk;
  int start = partial[i0] + boffs[i0 >> 8];
  int i1 = i0 + nchunk;
  int end = (b < 255) ? partial[i1] + boffs[i1 >> 8] : E;
  lh[t] = 0;
  __syncthreads();
  for (int p = start + t; p < end; p += 256) atomicAdd(&lh[ebuck[p] & 255], 1);
  __syncthreads();
  int val = lh[t];
  sm[t] = val;
  __syncthreads();
  for (int off = 1; off < 256; off <<= 1) {
    int v = (t >= off) ? sm[t - off] : 0;
    __syncthreads();
    sm[t] += v;
    __syncthreads();
  }
  lscan[t] = sm[t] - val;
  int node = b * 256 + t;
  if (node < N) offs_r[node] = start + lscan[t];
  if (b == 0 && t == 0) offs_r[N] = E;
  lh[t] = 0;
  __syncthreads();
  for (int p = start + t; p < end; p += 256) {
    int v = ebuck[p];
    int low = v & 255;
    int rk = atomicAdd(&lh[low], 1);
    perm_r[start + lscan[low] + rk] = v >> 8;
  }
}

// per-bucket finalize (col): emits pstat[pc]=(row,rowCSR-slot)
__global__ __launch_bounds__(256) void k_final_col(
    const int* __restrict__ ebuck, const int* __restrict__ perm_r,
    const int* __restrict__ row, const int* __restrict__ partial,
    const int* __restrict__ boffs, int2* __restrict__ pstat,
    int* __restrict__ offs_c, int nchunk, int N, int E) {
  __shared__ int lh[256], sm[256], lscan[256];
  int t = threadIdx.x, b = blockIdx.x;
  int i0 = b * nchunk;
  int start = partial[i0] + boffs[i0 >> 8];
  int i1 = i0 + nchunk;
  int end = (b < 255) ? partial[i1] + boffs[i1 >> 8] : E;
  lh[t] = 0;
  __syncthreads();
  for (int p = start + t; p < end; p += 256) atomicAdd(&lh[ebuck[p] & 255], 1);
  __syncthreads();
  int val = lh[t];
  sm[t] = val;
  __syncthreads();
  for (int off = 1; off < 256; off <<= 1) {
    int v = (t >= off) ? sm[t - off] : 0;
    __syncthreads();
    sm[t] += v;
    __syncthreads();
  }
  lscan[t] = sm[t] - val;
  int node = b * 256 + t;
  if (node < N) offs_c[node] = start + lscan[t];
  if (b == 0 && t == 0) offs_c[N] = E;
  lh[t] = 0;
  __syncthreads();
  for (int p = start + t; p < end; p += 256) {
    int v = ebuck[p];
    int low = v & 255;
    int rp = v >> 8;                      // rowCSR slot (~ascending -> L2 locality)
    int e = perm_r[rp];
    int rk = atomicAdd(&lh[low], 1);
    int2 rec; rec.x = row[e]; rec.y = rp;
    pstat[start + lscan[low] + rk] = rec;
  }
}

// ==== FUSED: simw (blocks [0,nw4)) + gemm128 (blocks [nw4, nw4+gb)) =========
// Independent workloads co-scheduled in one dispatch: simw is latency/fetch-
// bound, gemm is VALU/LDS-dense — waves overlap (m114). Shared-LDS union.
__global__ __launch_bounds__(256) void k_simw_gemm(
    // simw args
    const float* __restrict__ xn, const __hip_bfloat16* __restrict__ xnb,
    const int* __restrict__ colof_r, const int* __restrict__ offs_r,
    float* __restrict__ adjr, float* __restrict__ wgr,
    const float* __restrict__ gate, int layer, int N, int nw4,
    // gemm args (doGemm=0 -> simw-only grid)
    const void* __restrict__ Av, int a_bf16, const float* __restrict__ W,
    __hip_bfloat16* __restrict__ gout, int doGemm) {
  __shared__ __align__(16) char smem[18432];
  if ((int)blockIdx.x < nw4) {
    // ---------------- simw body (R13/R15-measured best) ----------------
    float (*sims)[320] = (float(*)[320])smem;
    int (*scol)[320] = (int(*)[320])(smem + 5120);
    int w = threadIdx.x >> 6;
    int l = threadIdx.x & 63;
    int r = blockIdx.x * 4 + w;
    if (r >= N) return;
    int p0 = offs_r[r], p1 = offs_r[r + 1];
    int ne = p1 - p0;                     // ~17 (Poisson(16)+self), <320
    int quad = l >> 4;
    int m = l & 15;
    int qoff = quad * 8;
    const __hip_bfloat16* xr = xnb + (size_t)r * F;
    bf16x8 b0 = *(const bf16x8*)(xr + 0 * 32 + qoff);
    bf16x8 b1 = *(const bf16x8*)(xr + 1 * 32 + qoff);
    bf16x8 b2 = *(const bf16x8*)(xr + 2 * 32 + qoff);
    bf16x8 b3 = *(const bf16x8*)(xr + 3 * 32 + qoff);
    for (int tb = 0; tb < ne; tb += 16) {
      int ii = tb + m; if (ii > ne - 1) ii = ne - 1;
      int cm = colof_r[p0 + ii];
      if (quad == 0 && tb + m < ne) scol[w][tb + m] = cm;
      const __hip_bfloat16* xc = xnb + (size_t)cm * F;
      bf16x8 a0 = *(const bf16x8*)(xc + 0 * 32 + qoff);
      bf16x8 a1 = *(const bf16x8*)(xc + 1 * 32 + qoff);
      bf16x8 a2 = *(const bf16x8*)(xc + 2 * 32 + qoff);
      bf16x8 a3 = *(const bf16x8*)(xc + 3 * 32 + qoff);
      f32x4 acc = {0.f, 0.f, 0.f, 0.f};
      acc = __builtin_amdgcn_mfma_f32_16x16x32_bf16(a0, b0, acc, 0, 0, 0);
      acc = __builtin_amdgcn_mfma_f32_16x16x32_bf16(a1, b1, acc, 0, 0, 0);
      acc = __builtin_amdgcn_mfma_f32_16x16x32_bf16(a2, b2, acc, 0, 0, 0);
      acc = __builtin_amdgcn_mfma_f32_16x16x32_bf16(a3, b3, acc, 0, 0, 0);
      if (m == 0) {
#pragma unroll
        for (int reg = 0; reg < 4; ++reg) {
          int i = tb + quad * 4 + reg;
          if (i < ne) sims[w][i] = acc[reg];
        }
      }
    }
    // guard-band fp32 recompute + threshold + rowsum/deg.
    // bf16 dot err <= 2^-7 = 0.0078 worst case; band +-0.01 covers it.
    float vsum = 0.f; int cn = 0;
    for (int base = 0; base < ne; base += 64) {
      int i = base + l;
      bool have = i < ne;
      float s = have ? sims[w][i] : 0.f;
      int c = have ? scol[w][i] : r;
      bool self = (c == r);
      bool flag = have && !self && fabsf(s - 0.1f) < 0.01f;
      unsigned long long mask = __ballot(flag);
      while (mask) {
        int src = __ffsll(mask) - 1;
        mask &= mask - 1;
        int cc = __shfl(c, src);
        float2 ar = ((const float2*)(xn + (size_t)r * F))[l];
        float2 bc = ((const float2*)(xn + (size_t)cc * F))[l];
        float d = ar.x * bc.x + ar.y * bc.y;
#pragma unroll
        for (int mm = 32; mm >= 1; mm >>= 1) d += __shfl_xor(d, mm);
        if (l == src) s = d;
      }
      if (self || s < 0.1f) s = 0.f;
      if (have) sims[w][i] = s;
      vsum += s;
      cn += (s > 0.f) ? 1 : 0;
    }
#pragma unroll
    for (int mm = 32; mm >= 1; mm >>= 1) {
      vsum += __shfl_xor(vsum, mm);
      cn += __shfl_xor(cn, mm);
    }
    float rs = vsum;
    float lam = 1.0f / (float)(cn + 1);
    float gg = (layer > 0) ? gate[layer - 1] : 0.f;
    for (int i = l; i < ne; i += 64) {
      int c = scol[w][i];
      float s = sims[w][i];
      float sn = (rs > 0.f) ? s / rs : 0.f;
      float wv = (c == r) ? lam : sn;
      wv = expf(wv);
      float wc;
      if (layer == 0) { adjr[p0 + i] = wv; wc = wv; }
      else { wc = gg * adjr[p0 + i] + (1.f - gg) * wv; }
      wgr[p0 + i] = wc;                 // sequential write; NO atomics
    }
  } else if (doGemm) {
    // ---------------- gemm128 body ----------------
    float (*As)[36] = (float(*)[36])smem;
    int t = threadIdx.x;
    int n0 = ((int)blockIdx.x - nw4) * 32;
    for (int i = t; i < 32 * 128; i += 256) {
      int nn = i >> 7, kk = i & 127;
      int gn = n0 + nn;
      float v = 0.f;
      if (gn < N) {
        if (a_bf16) v = __bfloat162float(((const __hip_bfloat16*)Av)[(size_t)gn * 128 + kk]);
        else v = ((const float*)Av)[(size_t)gn * 128 + kk];
      }
      As[kk][nn] = v;
    }
    __syncthreads();
    int nb = (t >> 6) * 8;
    int j2 = (t & 63) * 2;
    float acc[8][2] = {};
    for (int k = 0; k < 128; ++k) {
      float4 a01 = *(const float4*)&As[k][nb];
      float4 a23 = *(const float4*)&As[k][nb + 4];
      float2 wv = *(const float2*)&W[k * 128 + j2];
      acc[0][0] += a01.x * wv.x; acc[0][1] += a01.x * wv.y;
      acc[1][0] += a01.y * wv.x; acc[1][1] += a01.y * wv.y;
      acc[2][0] += a01.z * wv.x; acc[2][1] += a01.z * wv.y;
      acc[3][0] += a01.w * wv.x; acc[3][1] += a01.w * wv.y;
      acc[4][0] += a23.x * wv.x; acc[4][1] += a23.x * wv.y;
      acc[5][0] += a23.y * wv.x; acc[5][1] += a23.y * wv.y;
      acc[6][0] += a23.z * wv.x; acc[6][1] += a23.z * wv.y;
      acc[7][0] += a23.w * wv.x; acc[7][1] += a23.w * wv.y;
    }
    __hip_bfloat162* o2 = (__hip_bfloat162*)gout;
#pragma unroll
    for (int i = 0; i < 8; ++i) {
      int gn = n0 + nb + i;
      if (gn < N) {
        __hip_bfloat162 o;
        o.x = __float2bfloat16(acc[i][0]); o.y = __float2bfloat16(acc[i][1]);
        o2[(size_t)gn * 64 + (j2 >> 1)] = o;
      }
    }
  }
}

// ---- dinv[c] = rsqrt(sum of wc over col segment); no atomics ---------------
__global__ __launch_bounds__(256) void k_colw(
    const int2* __restrict__ pstat, const float* __restrict__ wgr,
    const int* __restrict__ offs_c, float* __restrict__ dinv, int N) {
  int c = blockIdx.x * 256 + threadIdx.x;
  if (c >= N) return;
  int p0 = offs_c[c], p1 = offs_c[c + 1];
  float s = 0.f;
  int p = p0;
  for (; p + 4 <= p1; p += 4) {        // 4 random L2 reads in flight
    int2 a = pstat[p], b = pstat[p + 1], d = pstat[p + 2], e = pstat[p + 3];
    s += wgr[a.y] + wgr[b.y] + wgr[d.y] + wgr[e.y];
  }
  for (; p < p1; ++p) s += wgr[pstat[p].y];
  dinv[c] = (s > 0.f) ? rsqrtf(s) : 0.f;
}

// ---- GEMM: out_bf16[M,40] = A_bf16[M,128] @ W[128,40] ----------------------
__global__ __launch_bounds__(320) void k_gemm40(const __hip_bfloat16* __restrict__ A,
                                                const float* __restrict__ W,
                                                __hip_bfloat16* __restrict__ out,
                                                int M, int C) {
  __shared__ float As[128][68];
  int t = threadIdx.x;
  int n0 = blockIdx.x * 64;
  for (int i = t; i < 64 * 128; i += 320) {
    int nn = i >> 7, kk = i & 127;
    int gn = n0 + nn;
    As[kk][nn] = (gn < M) ? __bfloat162float(A[(size_t)gn * 128 + kk]) : 0.f;
  }
  __syncthreads();
  int gq = t / 40;
  int jc = t - gq * 40;
  int nb = gq * 8;
  float acc[8] = {};
  for (int k = 0; k < 128; ++k) {
    float4 a01 = *(const float4*)&As[k][nb];
    float4 a23 = *(const float4*)&As[k][nb + 4];
    float wv = W[k * C + jc];
    acc[0] += a01.x * wv; acc[1] += a01.y * wv; acc[2] += a01.z * wv; acc[3] += a01.w * wv;
    acc[4] += a23.x * wv; acc[5] += a23.y * wv; acc[6] += a23.z * wv; acc[7] += a23.w * wv;
  }
#pragma unroll
  for (int i = 0; i < 8; ++i) {
    int gn = n0 + nb + i;
    if (gn < M) out[(size_t)gn * C + jc] = __float2bfloat16(acc[i]);
  }
}

// ---- aggregation + bias + relu + row-normalize; nrm inline via broadcast ---
// per-edge scalars (pstat/wgr/dinv) are wave-uniform -> 1 L2 request each.
__global__ __launch_bounds__(256) void k_agg_norm(
    const __hip_bfloat162* __restrict__ hWb, const int2* __restrict__ pstat,
    const float* __restrict__ wgr, const float* __restrict__ dinv,
    const int* __restrict__ offs_c, const float* __restrict__ bias,
    __hip_bfloat16* __restrict__ outb, float* __restrict__ xn,
    __hip_bfloat16* __restrict__ xnb, int N) {
  int w = threadIdx.x >> 6;
  int t = threadIdx.x & 63;
  int c = blockIdx.x * 4 + w;
  if (c >= N) return;
  int p0 = offs_c[c], p1 = offs_c[c + 1];
  float dic = dinv[c];
  float acc0 = bias[2 * t], acc1 = bias[2 * t + 1];
  int p = p0;
  for (; p + 8 <= p1; p += 8) {   // 8 row-gathers in flight
    int2 s[8];
    __hip_bfloat162 h[8];
    float nw[8];
#pragma unroll
    for (int k = 0; k < 8; ++k) s[k] = pstat[p + k];
#pragma unroll
    for (int k = 0; k < 8; ++k) h[k] = hWb[(size_t)s[k].x * 64 + t];
#pragma unroll
    for (int k = 0; k < 8; ++k) nw[k] = dinv[s[k].x] * wgr[s[k].y] * dic;
#pragma unroll
    for (int k = 0; k < 8; ++k) {
      acc0 += nw[k] * __bfloat162float(h[k].x);
      acc1 += nw[k] * __bfloat162float(h[k].y);
    }
  }
  for (; p < p1; ++p) {
    int2 s0 = pstat[p];
    __hip_bfloat162 h0 = hWb[(size_t)s0.x * 64 + t];
    float n0 = dinv[s0.x] * wgr[s0.y] * dic;
    acc0 += n0 * __bfloat162float(h0.x);
    acc1 += n0 * __bfloat162float(h0.y);
  }
  acc0 = fmaxf(acc0, 0.f); acc1 = fmaxf(acc1, 0.f);
  __hip_bfloat162 oh;                    // h stored bf16 (GEMM input next layer)
  oh.x = __float2bfloat16(acc0); oh.y = __float2bfloat16(acc1);
  ((__hip_bfloat162*)outb)[(size_t)c * 64 + t] = oh;
  float ss = acc0 * acc0 + acc1 * acc1;
#pragma unroll
  for (int m = 32; m >= 1; m >>= 1) ss += __shfl_xor(ss, m);
  float inv = 1.0f / fmaxf(sqrtf(ss), 1e-12f);
  float2 on; on.x = acc0 * inv; on.y = acc1 * inv;
  ((float2*)xn)[(size_t)c * 64 + t] = on;
  __hip_bfloat162 ob;
  ob.x = __float2bfloat16(on.x); ob.y = __float2bfloat16(on.y);
  ((__hip_bfloat162*)xnb)[(size_t)c * 64 + t] = ob;
}

// ------- final aggregation + bias + log_softmax; nrm inline -----------------
__global__ __launch_bounds__(256) void k_agg40_lsm(
    const __hip_bfloat16* __restrict__ hW, const int2* __restrict__ pstat,
    const float* __restrict__ wgr, const float* __restrict__ dinv,
    const int* __restrict__ offs_c, const float* __restrict__ bias,
    float* __restrict__ out, int C, int N) {
  int w = threadIdx.x >> 6;
  int j = threadIdx.x & 63;
  int c = blockIdx.x * 4 + w;
  if (c >= N) return;
  int p0 = offs_c[c], p1 = offs_c[c + 1];
  float dic = dinv[c];
  bool act = j < C;
  int jj = act ? j : 0;
  float acc = act ? bias[jj] : 0.f;
  int p = p0;
  for (; p + 4 <= p1; p += 4) {
    int2 s0 = pstat[p], s1 = pstat[p + 1], s2 = pstat[p + 2], s3 = pstat[p + 3];
    float h0 = __bfloat162float(hW[(size_t)s0.x * C + jj]);
    float h1 = __bfloat162float(hW[(size_t)s1.x * C + jj]);
    float h2 = __bfloat162float(hW[(size_t)s2.x * C + jj]);
    float h3 = __bfloat162float(hW[(size_t)s3.x * C + jj]);
    acc += dinv[s0.x] * wgr[s0.y] * dic * h0
         + dinv[s1.x] * wgr[s1.y] * dic * h1
         + dinv[s2.x] * wgr[s2.y] * dic * h2
         + dinv[s3.x] * wgr[s3.y] * dic * h3;
  }
  for (; p < p1; ++p) {
    int2 s0 = pstat[p];
    acc += dinv[s0.x] * wgr[s0.y] * dic
         * __bfloat162float(hW[(size_t)s0.x * C + jj]);
  }
  if (!act) acc = 0.f;
  float v = act ? acc : -3.0e38f;
#pragma unroll
  for (int m = 32; m >= 1; m >>= 1) v = fmaxf(v, __shfl_xor(v, m));
  float ex = act ? expf(acc - v) : 0.f;
#pragma unroll
  for (int m = 32; m >= 1; m >>= 1) ex += __shfl_xor(ex, m);
  if (act) out[(size_t)c * C + j] = acc - v - logf(ex);
}

extern "C" void kernel_launch(void* const* d_in, const int* in_sizes, int n_in,
                              void* d_out, int out_size, void* d_ws, size_t ws_size,
                              hipStream_t stream) {
  const float* x    = (const float*)d_in[0];
  const float* gate = (const float*)d_in[1];
  const float* W0   = (const float*)d_in[2];
  const float* b0   = (const float*)d_in[3];
  const float* W1   = (const float*)d_in[4];
  const float* b1   = (const float*)d_in[5];
  const float* W2   = (const float*)d_in[6];
  const float* b2   = (const float*)d_in[7];
  const int* eidx   = (const int*)d_in[8];
  int N = in_sizes[0] / 128;
  int E = in_sizes[8] / 2;
  int C = in_sizes[7];  // 40
  const int* row = eidx;
  const int* col = eidx + E;

  char* ws = (char*)d_ws;
  size_t off = 0;
  auto alloc = [&](size_t bytes) {
    char* p = ws + off;
    off += (bytes + 255) & ~(size_t)255;
    return p;
  };
  float* xn     = (float*)alloc((size_t)N * 128 * 4);
  __hip_bfloat16* xnb  = (__hip_bfloat16*)alloc((size_t)N * 128 * 2);
  __hip_bfloat16* bufC = (__hip_bfloat16*)alloc((size_t)N * 128 * 2);  // h, bf16
  __hip_bfloat16* hWb  = (__hip_bfloat16*)alloc((size_t)N * 128 * 2);
  float* adjr   = (float*)alloc((size_t)E * 4);    // layer-0 weights, row-CSR order
  float* wgr    = (float*)alloc((size_t)E * 4);    // gated weight, row-CSR order
  int*   perm_r = (int*)alloc((size_t)E * 4);
  int2*  pstat  = (int2*)alloc((size_t)E * 8);     // (row, rowCSR-slot) per col slot
  int*   colof_r= (int*)alloc((size_t)E * 4);
  int*   ebuck  = (int*)alloc((size_t)E * 4);      // bucket-partitioned packed ids
  int*   offs_c = (int*)alloc((size_t)(N + 1) * 4);
  int*   offs_r = (int*)alloc((size_t)(N + 1) * 4);
  float* dinv   = (float*)alloc((size_t)N * 4);

  int NCHUNK = (E + 2047) / 2048;
  int M      = 256 * NCHUNK;
  int*   ghist  = (int*)alloc((size_t)M * 4);
  int*   partial= (int*)alloc((size_t)M * 4);
  int*   bsum   = (int*)alloc((size_t)NCHUNK * 4);
  int*   boffs  = (int*)alloc((size_t)NCHUNK * 4);

  int NBUK = (N + 255) / 256;
  int nb1  = (N + 255) / 256;
  int nw4  = (N + 3) / 4;
  int gb128 = (N + 31) / 32;

  // ---- CSR build: atomic-free two-level counting sort (row, then col) ----
  k_lhist<<<NCHUNK, 256, 0, stream>>>(row, nullptr, ghist, nullptr, NCHUNK, E);
  k_scan1<<<NCHUNK, 256, 0, stream>>>(ghist, partial, bsum, M);
  k_scan2<<<1, 256, 0, stream>>>(bsum, boffs, NCHUNK);
  k_bucketize<<<NCHUNK, 256, 0, stream>>>(row, nullptr, partial, boffs, ebuck, NCHUNK, E);
  k_final_row<<<NBUK, 256, 0, stream>>>(ebuck, partial, boffs, perm_r, offs_r,
                                        NCHUNK, N, E);
  k_lhist<<<NCHUNK, 256, 0, stream>>>(col, perm_r, ghist, colof_r, NCHUNK, E);
  k_scan1<<<NCHUNK, 256, 0, stream>>>(ghist, partial, bsum, M);
  k_scan2<<<1, 256, 0, stream>>>(bsum, boffs, NCHUNK);
  k_bucketize<<<NCHUNK, 256, 0, stream>>>(col, perm_r, partial, boffs, ebuck, NCHUNK, E);
  k_final_col<<<NBUK, 256, 0, stream>>>(ebuck, perm_r, row, partial, boffs, pstat,
                                        offs_c, NCHUNK, N, E);

  for (int layer = 0; layer < 3; ++layer) {
    if (layer == 0) k_normalize<<<(N + 3) / 4, 256, 0, stream>>>(x, xn, xnb, N);
    if (layer < 2) {
      const float* W = (layer == 0) ? W0 : W1;
      const float* b = (layer == 0) ? b0 : b1;
      const void* Av = (layer == 0) ? (const void*)x : (const void*)bufC;
      int abf = (layer == 0) ? 0 : 1;
      k_simw_gemm<<<nw4 + gb128, 256, 0, stream>>>(xn, xnb, colof_r, offs_r, adjr, wgr,
                                                   gate, layer, N, nw4,
                                                   Av, abf, W, hWb, 1);
      k_colw<<<nb1, 256, 0, stream>>>(pstat, wgr, offs_c, dinv, N);
      k_agg_norm<<<nw4, 256, 0, stream>>>((const __hip_bfloat162*)hWb, pstat, wgr, dinv,
                                          offs_c, b, bufC, xn, xnb, N);
    } else {
      k_simw_gemm<<<nw4, 256, 0, stream>>>(xn, xnb, colof_r, offs_r, adjr, wgr,
                                           gate, layer, N, nw4,
                                           nullptr, 0, nullptr, nullptr, 0);
      k_colw<<<nb1, 256, 0, stream>>>(pstat, wgr, offs_c, dinv, N);
      k_gemm40<<<(N + 63) / 64, 320, 0, stream>>>(bufC, W2, hWb, N, C);
      k_agg40_lsm<<<nw4, 256, 0, stream>>>(hWb, pstat, wgr, dinv, offs_c, b2,
                                           (float*)d_out, C, N);
    }
  }
}

// Round 17
// 580.090 us; speedup vs baseline: 1.0590x; 1.0173x over previous
//
#include <hip/hip_runtime.h>
#include <hip/hip_bf16.h>
#include <math.h>

#define F 128

typedef __attribute__((ext_vector_type(8))) short bf16x8;
typedef __attribute__((ext_vector_type(4))) float f32x4;

// ------- row-normalize: xn = x/max(||x||,eps) (fp32 + bf16 copies) ----------
__global__ void k_normalize(const float* __restrict__ x, float* __restrict__ xn,
                            __hip_bfloat16* __restrict__ xnb, int N) {
  int wid = (blockIdx.x * blockDim.x + threadIdx.x) >> 6;  // one wave per node
  int lane = threadIdx.x & 63;
  if (wid >= N) return;
  const float2* src = (const float2*)(x + (size_t)wid * F);
  float2 v = src[lane];
  float ss = v.x * v.x + v.y * v.y;
#pragma unroll
  for (int m = 32; m >= 1; m >>= 1) ss += __shfl_xor(ss, m);
  float inv = 1.0f / fmaxf(sqrtf(ss), 1e-12f);
  float2 o; o.x = v.x * inv; o.y = v.y * inv;
  ((float2*)(xn + (size_t)wid * F))[lane] = o;
  __hip_bfloat162 ob;
  ob.x = __float2bfloat16(o.x); ob.y = __float2bfloat16(o.y);
  ((__hip_bfloat162*)(xnb + (size_t)wid * F))[lane] = ob;
}

// ============ CSR build: atomic-free two-level LDS counting sort ============
__global__ __launch_bounds__(256) void k_lhist(
    const int* __restrict__ keys, const int* __restrict__ perm,
    int* __restrict__ ghist, int* __restrict__ keyout, int nchunk, int E) {
  __shared__ int lh[256];
  int t = threadIdx.x, chunk = blockIdx.x;
  lh[t] = 0;
  __syncthreads();
  int base = chunk * 2048;
#pragma unroll
  for (int k = 0; k < 8; ++k) {
    int i = base + k * 256 + t;
    if (i < E) {
      int key = perm ? keys[perm[i]] : keys[i];
      if (keyout) keyout[i] = key;
      atomicAdd(&lh[key >> 8], 1);
    }
  }
  __syncthreads();
  ghist[t * nchunk + chunk] = lh[t];
}

__global__ void k_scan1(const int* __restrict__ cnt, int* __restrict__ partial,
                        int* __restrict__ bsum, int M) {
  __shared__ int sm[256];
  int t = threadIdx.x;
  int i = blockIdx.x * 256 + t;
  int val = (i < M) ? cnt[i] : 0;
  sm[t] = val;
  __syncthreads();
  for (int off = 1; off < 256; off <<= 1) {
    int v = (t >= off) ? sm[t - off] : 0;
    __syncthreads();
    sm[t] += v;
    __syncthreads();
  }
  if (i < M) partial[i] = sm[t] - val;  // exclusive
  if (t == 255) bsum[blockIdx.x] = sm[255];
}

__global__ void k_scan2(const int* __restrict__ bsum, int* __restrict__ boffs, int nb) {
  __shared__ int sm[256];
  int t = threadIdx.x;
  int carry = 0;
  for (int base = 0; base < nb; base += 256) {
    int idx = base + t;
    int val = (idx < nb) ? bsum[idx] : 0;
    sm[t] = val;
    __syncthreads();
    for (int off = 1; off < 256; off <<= 1) {
      int v = (t >= off) ? sm[t - off] : 0;
      __syncthreads();
      sm[t] += v;
      __syncthreads();
    }
    if (idx < nb) boffs[idx] = sm[t] - val + carry;
    carry += sm[255];
    __syncthreads();
  }
}

__global__ __launch_bounds__(256) void k_bucketize(
    const int* __restrict__ keys, const int* __restrict__ perm,
    const int* __restrict__ partial, const int* __restrict__ boffs,
    int* __restrict__ ebuck, int nchunk, int E) {
  __shared__ int lcur[256];
  int t = threadIdx.x, chunk = blockIdx.x;
  int idx = t * nchunk + chunk;
  lcur[t] = partial[idx] + boffs[idx >> 8];
  __syncthreads();
  int base = chunk * 2048;
#pragma unroll
  for (int k = 0; k < 8; ++k) {
    int i = base + k * 256 + t;
    if (i < E) {
      int key = perm ? keys[perm[i]] : keys[i];
      int pos = atomicAdd(&lcur[key >> 8], 1);
      ebuck[pos] = (i << 8) | (key & 255);
    }
  }
}

__global__ __launch_bounds__(256) void k_final_row(
    const int* __restrict__ ebuck, const int* __restrict__ partial,
    const int* __restrict__ boffs, int* __restrict__ perm_r,
    int* __restrict__ offs_r, int nchunk, int N, int E) {
  __shared__ int lh[256], sm[256], lscan[256];
  int t = threadIdx.x, b = blockIdx.x;
  int i0 = b * nchunk;
  int start = partial[i0] + boffs[i0 >> 8];
  int i1 = i0 + nchunk;
  int end = (b < 255) ? partial[i1] + boffs[i1 >> 8] : E;
  lh[t] = 0;
  __syncthreads();
  for (int p = start + t; p < end; p += 256) atomicAdd(&lh[ebuck[p] & 255], 1);
  __syncthreads();
  int val = lh[t];
  sm[t] = val;
  __syncthreads();
  for (int off = 1; off < 256; off <<= 1) {
    int v = (t >= off) ? sm[t - off] : 0;
    __syncthreads();
    sm[t] += v;
    __syncthreads();
  }
  lscan[t] = sm[t] - val;
  int node = b * 256 + t;
  if (node < N) offs_r[node] = start + lscan[t];
  if (b == 0 && t == 0) offs_r[N] = E;
  lh[t] = 0;
  __syncthreads();
  for (int p = start + t; p < end; p += 256) {
    int v = ebuck[p];
    int low = v & 255;
    int rk = atomicAdd(&lh[low], 1);
    perm_r[start + lscan[low] + rk] = v >> 8;
  }
}

// per-bucket finalize (col): emits pstat[pc]=(row,rowCSR-slot)
__global__ __launch_bounds__(256) void k_final_col(
    const int* __restrict__ ebuck, const int* __restrict__ perm_r,
    const int* __restrict__ row, const int* __restrict__ partial,
    const int* __restrict__ boffs, int2* __restrict__ pstat,
    int* __restrict__ offs_c, int nchunk, int N, int E) {
  __shared__ int lh[256], sm[256], lscan[256];
  int t = threadIdx.x, b = blockIdx.x;
  int i0 = b * nchunk;
  int start = partial[i0] + boffs[i0 >> 8];
  int i1 = i0 + nchunk;
  int end = (b < 255) ? partial[i1] + boffs[i1 >> 8] : E;
  lh[t] = 0;
  __syncthreads();
  for (int p = start + t; p < end; p += 256) atomicAdd(&lh[ebuck[p] & 255], 1);
  __syncthreads();
  int val = lh[t];
  sm[t] = val;
  __syncthreads();
  for (int off = 1; off < 256; off <<= 1) {
    int v = (t >= off) ? sm[t - off] : 0;
    __syncthreads();
    sm[t] += v;
    __syncthreads();
  }
  lscan[t] = sm[t] - val;
  int node = b * 256 + t;
  if (node < N) offs_c[node] = start + lscan[t];
  if (b == 0 && t == 0) offs_c[N] = E;
  lh[t] = 0;
  __syncthreads();
  for (int p = start + t; p < end; p += 256) {
    int v = ebuck[p];
    int low = v & 255;
    int rp = v >> 8;                      // rowCSR slot (~ascending -> L2 locality)
    int e = perm_r[rp];
    int rk = atomicAdd(&lh[low], 1);
    int2 rec; rec.x = row[e]; rec.y = rp;
    pstat[start + lscan[low] + rk] = rec;
  }
}

// ==== FUSED: gemm128 (blocks [0,gb)) FIRST + simw (blocks [gb, gb+nw4)) =====
// gemm blocks dispatch first -> their VALU-dense waves overlap simw's
// latency-bound waves for the whole kernel instead of trailing (R16 lesson).
__global__ __launch_bounds__(256) void k_simw_gemm(
    // simw args
    const float* __restrict__ xn, const __hip_bfloat16* __restrict__ xnb,
    const int* __restrict__ colof_r, const int* __restrict__ offs_r,
    float* __restrict__ adjr, float* __restrict__ wgr,
    const float* __restrict__ gate, int layer, int N, int gb,
    // gemm args (gb=0 -> simw-only grid)
    const void* __restrict__ Av, int a_bf16, const float* __restrict__ W,
    __hip_bfloat16* __restrict__ gout) {
  __shared__ __align__(16) char smem[18432];
  if ((int)blockIdx.x >= gb) {
    // ---------------- simw body (R13/R15-measured best) ----------------
    float (*sims)[320] = (float(*)[320])smem;
    int (*scol)[320] = (int(*)[320])(smem + 5120);
    int w = threadIdx.x >> 6;
    int l = threadIdx.x & 63;
    int r = ((int)blockIdx.x - gb) * 4 + w;
    if (r >= N) return;
    int p0 = offs_r[r], p1 = offs_r[r + 1];
    int ne = p1 - p0;                     // ~17 (Poisson(16)+self), <320
    int quad = l >> 4;
    int m = l & 15;
    int qoff = quad * 8;
    const __hip_bfloat16* xr = xnb + (size_t)r * F;
    bf16x8 b0 = *(const bf16x8*)(xr + 0 * 32 + qoff);
    bf16x8 b1 = *(const bf16x8*)(xr + 1 * 32 + qoff);
    bf16x8 b2 = *(const bf16x8*)(xr + 2 * 32 + qoff);
    bf16x8 b3 = *(const bf16x8*)(xr + 3 * 32 + qoff);
    for (int tb = 0; tb < ne; tb += 16) {
      int ii = tb + m; if (ii > ne - 1) ii = ne - 1;
      int cm = colof_r[p0 + ii];
      if (quad == 0 && tb + m < ne) scol[w][tb + m] = cm;
      const __hip_bfloat16* xc = xnb + (size_t)cm * F;
      bf16x8 a0 = *(const bf16x8*)(xc + 0 * 32 + qoff);
      bf16x8 a1 = *(const bf16x8*)(xc + 1 * 32 + qoff);
      bf16x8 a2 = *(const bf16x8*)(xc + 2 * 32 + qoff);
      bf16x8 a3 = *(const bf16x8*)(xc + 3 * 32 + qoff);
      f32x4 acc = {0.f, 0.f, 0.f, 0.f};
      acc = __builtin_amdgcn_mfma_f32_16x16x32_bf16(a0, b0, acc, 0, 0, 0);
      acc = __builtin_amdgcn_mfma_f32_16x16x32_bf16(a1, b1, acc, 0, 0, 0);
      acc = __builtin_amdgcn_mfma_f32_16x16x32_bf16(a2, b2, acc, 0, 0, 0);
      acc = __builtin_amdgcn_mfma_f32_16x16x32_bf16(a3, b3, acc, 0, 0, 0);
      if (m == 0) {
#pragma unroll
        for (int reg = 0; reg < 4; ++reg) {
          int i = tb + quad * 4 + reg;
          if (i < ne) sims[w][i] = acc[reg];
        }
      }
    }
    // guard-band fp32 recompute + threshold + rowsum/deg.
    // bf16 dot err <= 2^-7 = 0.0078 worst case; band +-0.01 covers it.
    float vsum = 0.f; int cn = 0;
    for (int base = 0; base < ne; base += 64) {
      int i = base + l;
      bool have = i < ne;
      float s = have ? sims[w][i] : 0.f;
      int c = have ? scol[w][i] : r;
      bool self = (c == r);
      bool flag = have && !self && fabsf(s - 0.1f) < 0.01f;
      unsigned long long mask = __ballot(flag);
      while (mask) {
        int src = __ffsll(mask) - 1;
        mask &= mask - 1;
        int cc = __shfl(c, src);
        float2 ar = ((const float2*)(xn + (size_t)r * F))[l];
        float2 bc = ((const float2*)(xn + (size_t)cc * F))[l];
        float d = ar.x * bc.x + ar.y * bc.y;
#pragma unroll
        for (int mm = 32; mm >= 1; mm >>= 1) d += __shfl_xor(d, mm);
        if (l == src) s = d;
      }
      if (self || s < 0.1f) s = 0.f;
      if (have) sims[w][i] = s;
      vsum += s;
      cn += (s > 0.f) ? 1 : 0;
    }
#pragma unroll
    for (int mm = 32; mm >= 1; mm >>= 1) {
      vsum += __shfl_xor(vsum, mm);
      cn += __shfl_xor(cn, mm);
    }
    float rs = vsum;
    float lam = 1.0f / (float)(cn + 1);
    float gg = (layer > 0) ? gate[layer - 1] : 0.f;
    for (int i = l; i < ne; i += 64) {
      int c = scol[w][i];
      float s = sims[w][i];
      float sn = (rs > 0.f) ? s / rs : 0.f;
      float wv = (c == r) ? lam : sn;
      wv = expf(wv);
      float wc;
      if (layer == 0) { adjr[p0 + i] = wv; wc = wv; }
      else { wc = gg * adjr[p0 + i] + (1.f - gg) * wv; }
      wgr[p0 + i] = wc;                 // sequential write; NO atomics
    }
  } else {
    // ---------------- gemm128 body ----------------
    float (*As)[36] = (float(*)[36])smem;
    int t = threadIdx.x;
    int n0 = (int)blockIdx.x * 32;
    for (int i = t; i < 32 * 128; i += 256) {
      int nn = i >> 7, kk = i & 127;
      int gn = n0 + nn;
      float v = 0.f;
      if (gn < N) {
        if (a_bf16) v = __bfloat162float(((const __hip_bfloat16*)Av)[(size_t)gn * 128 + kk]);
        else v = ((const float*)Av)[(size_t)gn * 128 + kk];
      }
      As[kk][nn] = v;
    }
    __syncthreads();
    int nb = (t >> 6) * 8;
    int j2 = (t & 63) * 2;
    float acc[8][2] = {};
    for (int k = 0; k < 128; ++k) {
      float4 a01 = *(const float4*)&As[k][nb];
      float4 a23 = *(const float4*)&As[k][nb + 4];
      float2 wv = *(const float2*)&W[k * 128 + j2];
      acc[0][0] += a01.x * wv.x; acc[0][1] += a01.x * wv.y;
      acc[1][0] += a01.y * wv.x; acc[1][1] += a01.y * wv.y;
      acc[2][0] += a01.z * wv.x; acc[2][1] += a01.z * wv.y;
      acc[3][0] += a01.w * wv.x; acc[3][1] += a01.w * wv.y;
      acc[4][0] += a23.x * wv.x; acc[4][1] += a23.x * wv.y;
      acc[5][0] += a23.y * wv.x; acc[5][1] += a23.y * wv.y;
      acc[6][0] += a23.z * wv.x; acc[6][1] += a23.z * wv.y;
      acc[7][0] += a23.w * wv.x; acc[7][1] += a23.w * wv.y;
    }
    __hip_bfloat162* o2 = (__hip_bfloat162*)gout;
#pragma unroll
    for (int i = 0; i < 8; ++i) {
      int gn = n0 + nb + i;
      if (gn < N) {
        __hip_bfloat162 o;
        o.x = __float2bfloat16(acc[i][0]); o.y = __float2bfloat16(acc[i][1]);
        o2[(size_t)gn * 64 + (j2 >> 1)] = o;
      }
    }
  }
}

// ---- dinv[c] = rsqrt(sum of wc over col segment); no atomics ---------------
__global__ __launch_bounds__(256) void k_colw(
    const int2* __restrict__ pstat, const float* __restrict__ wgr,
    const int* __restrict__ offs_c, float* __restrict__ dinv, int N) {
  int c = blockIdx.x * 256 + threadIdx.x;
  if (c >= N) return;
  int p0 = offs_c[c], p1 = offs_c[c + 1];
  float s = 0.f;
  int p = p0;
  for (; p + 4 <= p1; p += 4) {        // 4 random L2 reads in flight
    int2 a = pstat[p], b = pstat[p + 1], d = pstat[p + 2], e = pstat[p + 3];
    s += wgr[a.y] + wgr[b.y] + wgr[d.y] + wgr[e.y];
  }
  for (; p < p1; ++p) s += wgr[pstat[p].y];
  dinv[c] = (s > 0.f) ? rsqrtf(s) : 0.f;
}

// ---- GEMM: out_bf16[M,40] = A_bf16[M,128] @ W[128,40] ----------------------
__global__ __launch_bounds__(320) void k_gemm40(const __hip_bfloat16* __restrict__ A,
                                                const float* __restrict__ W,
                                                __hip_bfloat16* __restrict__ out,
                                                int M, int C) {
  __shared__ float As[128][68];
  int t = threadIdx.x;
  int n0 = blockIdx.x * 64;
  for (int i = t; i < 64 * 128; i += 320) {
    int nn = i >> 7, kk = i & 127;
    int gn = n0 + nn;
    As[kk][nn] = (gn < M) ? __bfloat162float(A[(size_t)gn * 128 + kk]) : 0.f;
  }
  __syncthreads();
  int gq = t / 40;
  int jc = t - gq * 40;
  int nb = gq * 8;
  float acc[8] = {};
  for (int k = 0; k < 128; ++k) {
    float4 a01 = *(const float4*)&As[k][nb];
    float4 a23 = *(const float4*)&As[k][nb + 4];
    float wv = W[k * C + jc];
    acc[0] += a01.x * wv; acc[1] += a01.y * wv; acc[2] += a01.z * wv; acc[3] += a01.w * wv;
    acc[4] += a23.x * wv; acc[5] += a23.y * wv; acc[6] += a23.z * wv; acc[7] += a23.w * wv;
  }
#pragma unroll
  for (int i = 0; i < 8; ++i) {
    int gn = n0 + nb + i;
    if (gn < M) out[(size_t)gn * C + jc] = __float2bfloat16(acc[i]);
  }
}

// ---- aggregation + bias + relu + row-normalize; nrm inline via broadcast ---
__global__ __launch_bounds__(256) void k_agg_norm(
    const __hip_bfloat162* __restrict__ hWb, const int2* __restrict__ pstat,
    const float* __restrict__ wgr, const float* __restrict__ dinv,
    const int* __restrict__ offs_c, const float* __restrict__ bias,
    __hip_bfloat16* __restrict__ outb, float* __restrict__ xn,
    __hip_bfloat16* __restrict__ xnb, int N) {
  int w = threadIdx.x >> 6;
  int t = threadIdx.x & 63;
  int c = blockIdx.x * 4 + w;
  if (c >= N) return;
  int p0 = offs_c[c], p1 = offs_c[c + 1];
  float dic = dinv[c];
  float acc0 = bias[2 * t], acc1 = bias[2 * t + 1];
  int p = p0;
  for (; p + 8 <= p1; p += 8) {   // 8 row-gathers in flight
    int2 s[8];
    __hip_bfloat162 h[8];
    float nw[8];
#pragma unroll
    for (int k = 0; k < 8; ++k) s[k] = pstat[p + k];
#pragma unroll
    for (int k = 0; k < 8; ++k) h[k] = hWb[(size_t)s[k].x * 64 + t];
#pragma unroll
    for (int k = 0; k < 8; ++k) nw[k] = dinv[s[k].x] * wgr[s[k].y] * dic;
#pragma unroll
    for (int k = 0; k < 8; ++k) {
      acc0 += nw[k] * __bfloat162float(h[k].x);
      acc1 += nw[k] * __bfloat162float(h[k].y);
    }
  }
  for (; p < p1; ++p) {
    int2 s0 = pstat[p];
    __hip_bfloat162 h0 = hWb[(size_t)s0.x * 64 + t];
    float n0 = dinv[s0.x] * wgr[s0.y] * dic;
    acc0 += n0 * __bfloat162float(h0.x);
    acc1 += n0 * __bfloat162float(h0.y);
  }
  acc0 = fmaxf(acc0, 0.f); acc1 = fmaxf(acc1, 0.f);
  __hip_bfloat162 oh;                    // h stored bf16 (GEMM input next layer)
  oh.x = __float2bfloat16(acc0); oh.y = __float2bfloat16(acc1);
  ((__hip_bfloat162*)outb)[(size_t)c * 64 + t] = oh;
  float ss = acc0 * acc0 + acc1 * acc1;
#pragma unroll
  for (int m = 32; m >= 1; m >>= 1) ss += __shfl_xor(ss, m);
  float inv = 1.0f / fmaxf(sqrtf(ss), 1e-12f);
  float2 on; on.x = acc0 * inv; on.y = acc1 * inv;
  ((float2*)xn)[(size_t)c * 64 + t] = on;
  __hip_bfloat162 ob;
  ob.x = __float2bfloat16(on.x); ob.y = __float2bfloat16(on.y);
  ((__hip_bfloat162*)xnb)[(size_t)c * 64 + t] = ob;
}

// ------- final aggregation + bias + log_softmax; nrm inline -----------------
__global__ __launch_bounds__(256) void k_agg40_lsm(
    const __hip_bfloat16* __restrict__ hW, const int2* __restrict__ pstat,
    const float* __restrict__ wgr, const float* __restrict__ dinv,
    const int* __restrict__ offs_c, const float* __restrict__ bias,
    float* __restrict__ out, int C, int N) {
  int w = threadIdx.x >> 6;
  int j = threadIdx.x & 63;
  int c = blockIdx.x * 4 + w;
  if (c >= N) return;
  int p0 = offs_c[c], p1 = offs_c[c + 1];
  float dic = dinv[c];
  bool act = j < C;
  int jj = act ? j : 0;
  float acc = act ? bias[jj] : 0.f;
  int p = p0;
  for (; p + 4 <= p1; p += 4) {
    int2 s0 = pstat[p], s1 = pstat[p + 1], s2 = pstat[p + 2], s3 = pstat[p + 3];
    float h0 = __bfloat162float(hW[(size_t)s0.x * C + jj]);
    float h1 = __bfloat162float(hW[(size_t)s1.x * C + jj]);
    float h2 = __bfloat162float(hW[(size_t)s2.x * C + jj]);
    float h3 = __bfloat162float(hW[(size_t)s3.x * C + jj]);
    acc += dinv[s0.x] * wgr[s0.y] * dic * h0
         + dinv[s1.x] * wgr[s1.y] * dic * h1
         + dinv[s2.x] * wgr[s2.y] * dic * h2
         + dinv[s3.x] * wgr[s3.y] * dic * h3;
  }
  for (; p < p1; ++p) {
    int2 s0 = pstat[p];
    acc += dinv[s0.x] * wgr[s0.y] * dic
         * __bfloat162float(hW[(size_t)s0.x * C + jj]);
  }
  if (!act) acc = 0.f;
  float v = act ? acc : -3.0e38f;
#pragma unroll
  for (int m = 32; m >= 1; m >>= 1) v = fmaxf(v, __shfl_xor(v, m));
  float ex = act ? expf(acc - v) : 0.f;
#pragma unroll
  for (int m = 32; m >= 1; m >>= 1) ex += __shfl_xor(ex, m);
  if (act) out[(size_t)c * C + j] = acc - v - logf(ex);
}

extern "C" void kernel_launch(void* const* d_in, const int* in_sizes, int n_in,
                              void* d_out, int out_size, void* d_ws, size_t ws_size,
                              hipStream_t stream) {
  const float* x    = (const float*)d_in[0];
  const float* gate = (const float*)d_in[1];
  const float* W0   = (const float*)d_in[2];
  const float* b0   = (const float*)d_in[3];
  const float* W1   = (const float*)d_in[4];
  const float* b1   = (const float*)d_in[5];
  const float* W2   = (const float*)d_in[6];
  const float* b2   = (const float*)d_in[7];
  const int* eidx   = (const int*)d_in[8];
  int N = in_sizes[0] / 128;
  int E = in_sizes[8] / 2;
  int C = in_sizes[7];  // 40
  const int* row = eidx;
  const int* col = eidx + E;

  char* ws = (char*)d_ws;
  size_t off = 0;
  auto alloc = [&](size_t bytes) {
    char* p = ws + off;
    off += (bytes + 255) & ~(size_t)255;
    return p;
  };
  float* xn     = (float*)alloc((size_t)N * 128 * 4);
  __hip_bfloat16* xnb  = (__hip_bfloat16*)alloc((size_t)N * 128 * 2);
  __hip_bfloat16* bufC = (__hip_bfloat16*)alloc((size_t)N * 128 * 2);  // h, bf16
  __hip_bfloat16* hWb  = (__hip_bfloat16*)alloc((size_t)N * 128 * 2);
  float* adjr   = (float*)alloc((size_t)E * 4);    // layer-0 weights, row-CSR order
  float* wgr    = (float*)alloc((size_t)E * 4);    // gated weight, row-CSR order
  int*   perm_r = (int*)alloc((size_t)E * 4);
  int2*  pstat  = (int2*)alloc((size_t)E * 8);     // (row, rowCSR-slot) per col slot
  int*   colof_r= (int*)alloc((size_t)E * 4);
  int*   ebuck  = (int*)alloc((size_t)E * 4);      // bucket-partitioned packed ids
  int*   offs_c = (int*)alloc((size_t)(N + 1) * 4);
  int*   offs_r = (int*)alloc((size_t)(N + 1) * 4);
  float* dinv   = (float*)alloc((size_t)N * 4);

  int NCHUNK = (E + 2047) / 2048;
  int M      = 256 * NCHUNK;
  int*   ghist  = (int*)alloc((size_t)M * 4);
  int*   partial= (int*)alloc((size_t)M * 4);
  int*   bsum   = (int*)alloc((size_t)NCHUNK * 4);
  int*   boffs  = (int*)alloc((size_t)NCHUNK * 4);

  int NBUK = (N + 255) / 256;
  int nb1  = (N + 255) / 256;
  int nw4  = (N + 3) / 4;
  int gb128 = (N + 31) / 32;

  // ---- CSR build: atomic-free two-level counting sort (row, then col) ----
  k_lhist<<<NCHUNK, 256, 0, stream>>>(row, nullptr, ghist, nullptr, NCHUNK, E);
  k_scan1<<<NCHUNK, 256, 0, stream>>>(ghist, partial, bsum, M);
  k_scan2<<<1, 256, 0, stream>>>(bsum, boffs, NCHUNK);
  k_bucketize<<<NCHUNK, 256, 0, stream>>>(row, nullptr, partial, boffs, ebuck, NCHUNK, E);
  k_final_row<<<NBUK, 256, 0, stream>>>(ebuck, partial, boffs, perm_r, offs_r,
                                        NCHUNK, N, E);
  k_lhist<<<NCHUNK, 256, 0, stream>>>(col, perm_r, ghist, colof_r, NCHUNK, E);
  k_scan1<<<NCHUNK, 256, 0, stream>>>(ghist, partial, bsum, M);
  k_scan2<<<1, 256, 0, stream>>>(bsum, boffs, NCHUNK);
  k_bucketize<<<NCHUNK, 256, 0, stream>>>(col, perm_r, partial, boffs, ebuck, NCHUNK, E);
  k_final_col<<<NBUK, 256, 0, stream>>>(ebuck, perm_r, row, partial, boffs, pstat,
                                        offs_c, NCHUNK, N, E);

  for (int layer = 0; layer < 3; ++layer) {
    if (layer == 0) k_normalize<<<(N + 3) / 4, 256, 0, stream>>>(x, xn, xnb, N);
    if (layer < 2) {
      const float* W = (layer == 0) ? W0 : W1;
      const float* b = (layer == 0) ? b0 : b1;
      const void* Av = (layer == 0) ? (const void*)x : (const void*)bufC;
      int abf = (layer == 0) ? 0 : 1;
      k_simw_gemm<<<gb128 + nw4, 256, 0, stream>>>(xn, xnb, colof_r, offs_r, adjr, wgr,
                                                   gate, layer, N, gb128,
                                                   Av, abf, W, hWb);
      k_colw<<<nb1, 256, 0, stream>>>(pstat, wgr, offs_c, dinv, N);
      k_agg_norm<<<nw4, 256, 0, stream>>>((const __hip_bfloat162*)hWb, pstat, wgr, dinv,
                                          offs_c, b, bufC, xn, xnb, N);
    } else {
      k_simw_gemm<<<nw4, 256, 0, stream>>>(xn, xnb, colof_r, offs_r, adjr, wgr,
                                           gate, layer, N, 0,
                                           nullptr, 0, nullptr, nullptr);
      k_colw<<<nb1, 256, 0, stream>>>(pstat, wgr, offs_c, dinv, N);
      k_gemm40<<<(N + 63) / 64, 320, 0, stream>>>(bufC, W2, hWb, N, C);
      k_agg40_lsm<<<nw4, 256, 0, stream>>>(hWb, pstat, wgr, dinv, offs_c, b2,
                                           (float*)d_out, C, N);
    }
  }
}